// Round 1
// baseline (688.474 us; speedup 1.0000x reference)
//
#include <hip/hip_runtime.h>
#include <math.h>

#define N_NODES 50000
#define N_EDGES 800000
#define F_IN    128
#define HID     64
#define HEADS   2
#define C1      128   // HEADS*HID
#define OUT_C   40
#define EDIM    5
#define NEG_SLOPE 0.2f

// ---------------- workspace layout (element offsets, 4B units) ----------------
constexpr size_t pad64(size_t n){ return (n + 63) / 64 * 64; }
constexpr size_t O_CNT      = 0;
constexpr size_t O_FILL     = O_CNT      + pad64(N_NODES);
constexpr size_t O_SUMATTR  = O_FILL     + pad64(N_NODES);
constexpr size_t O_ZERO_END = O_SUMATTR  + pad64((size_t)N_NODES*EDIM);
constexpr size_t O_ROWPTR   = O_ZERO_END;
constexpr size_t O_COLSRC   = O_ROWPTR   + pad64(N_NODES+1);
constexpr size_t O_ALE1     = O_COLSRC   + pad64(N_EDGES);
constexpr size_t O_ALE2     = O_ALE1     + pad64((size_t)N_EDGES*2);
constexpr size_t O_WEATT    = O_ALE2     + pad64(N_EDGES);
constexpr size_t O_LOOP1    = O_WEATT    + 64;
constexpr size_t O_LOOP2    = O_LOOP1    + pad64((size_t)N_NODES*2);
constexpr size_t O_XH1      = O_LOOP2    + pad64(N_NODES);
constexpr size_t O_AS1      = O_XH1      + pad64((size_t)N_NODES*C1);
constexpr size_t O_AD1      = O_AS1      + pad64((size_t)N_NODES*2);
constexpr size_t O_H1       = O_AD1      + pad64((size_t)N_NODES*2);
constexpr size_t O_XH2      = O_H1       + pad64((size_t)N_NODES*C1);
constexpr size_t O_AS2      = O_XH2      + pad64((size_t)N_NODES*OUT_C);
constexpr size_t O_AD2      = O_AS2      + pad64(N_NODES);

__device__ __forceinline__ float lrelu(float v){ return v >= 0.f ? v : NEG_SLOPE*v; }

// online-softmax: add one logit with weight 1
__device__ __forceinline__ void sm_add(float& m, float& s, float l){
  if (l > m){ s = s*expf(m - l) + 1.f; m = l; }
  else      { s += expf(l - m); }
}
// merge two (max, sum) states; (mo,so) may be empty (so==0)
__device__ __forceinline__ void sm_merge(float& m, float& s, float mo, float so){
  if (so > 0.f){
    if (mo > m){ s = s*expf(m - mo) + so; m = mo; }
    else       { s += so*expf(mo - m); }
  }
}

// ---------------- K0: tiny attention-projection matrices ----------------
// weatt[k*2+h]  = sum_c We1[k,h*64+c]*att_e1[h,c]   (k<5,h<2)
// weatt[10+k]   = sum_c We2[k,c]*att_e2[c]
__global__ void k_weatt(const float* __restrict__ We1, const float* __restrict__ ae1,
                        const float* __restrict__ We2, const float* __restrict__ ae2,
                        float* __restrict__ weatt){
  int t = threadIdx.x;
  if (t < 10){
    int k = t >> 1, h = t & 1;
    float s = 0.f;
    for (int c = 0; c < HID; c++) s += We1[k*C1 + h*HID + c] * ae1[h*HID + c];
    weatt[k*2 + h] = s;
  } else if (t < 15){
    int k = t - 10;
    float s = 0.f;
    for (int c = 0; c < OUT_C; c++) s += We2[k*OUT_C + c] * ae2[c];
    weatt[10 + k] = s;
  }
}

// ---------------- K1: in-degree + edge-attr sums (for self-loop mean) ----------------
__global__ void k_count(const int* __restrict__ dst, const float* __restrict__ eattr,
                        int* __restrict__ cnt, float* __restrict__ sumattr){
  int e = blockIdx.x*blockDim.x + threadIdx.x;
  if (e >= N_EDGES) return;
  int d = dst[e];
  atomicAdd(&cnt[d], 1);
  #pragma unroll
  for (int k = 0; k < EDIM; k++) atomicAdd(&sumattr[d*EDIM + k], eattr[e*EDIM + k]);
}

// ---------------- K2: exclusive scan of cnt -> rowptr ----------------
__global__ void __launch_bounds__(1024) k_scan(const int* __restrict__ cnt, int* __restrict__ rowptr){
  __shared__ int part[1024];
  int t = threadIdx.x;
  const int CH = (N_NODES + 1023) / 1024;
  int base = t * CH;
  int s = 0;
  for (int i = 0; i < CH; i++){ int idx = base + i; if (idx < N_NODES) s += cnt[idx]; }
  part[t] = s; __syncthreads();
  for (int off = 1; off < 1024; off <<= 1){
    int v = (t >= off) ? part[t - off] : 0;
    __syncthreads();
    part[t] += v;
    __syncthreads();
  }
  int run = (t == 0) ? 0 : part[t - 1];
  for (int i = 0; i < CH; i++){
    int idx = base + i;
    if (idx < N_NODES){ rowptr[idx] = run; run += cnt[idx]; }
  }
  if (t == 1023) rowptr[N_NODES] = part[1023];
}

// ---------------- K3: scatter edges into CSR; precompute per-edge attn-attr dots ----------------
__global__ void k_scatter(const int* __restrict__ src, const int* __restrict__ dst,
                          const float* __restrict__ eattr, const int* __restrict__ rowptr,
                          int* __restrict__ fill, int* __restrict__ colsrc,
                          const float* __restrict__ weatt,
                          float* __restrict__ ale1, float* __restrict__ ale2){
  int e = blockIdx.x*blockDim.x + threadIdx.x;
  if (e >= N_EDGES) return;
  int d = dst[e];
  int pos = rowptr[d] + atomicAdd(&fill[d], 1);
  colsrc[pos] = src[e];
  float a[EDIM];
  #pragma unroll
  for (int k = 0; k < EDIM; k++) a[k] = eattr[e*EDIM + k];
  float l0 = 0.f, l1 = 0.f, l2 = 0.f;
  #pragma unroll
  for (int k = 0; k < EDIM; k++){
    l0 += a[k]*weatt[k*2 + 0];
    l1 += a[k]*weatt[k*2 + 1];
    l2 += a[k]*weatt[10 + k];
  }
  ale1[pos*2 + 0] = l0; ale1[pos*2 + 1] = l1; ale2[pos] = l2;
}

// ---------------- K4: self-loop attr means -> attn dots ----------------
__global__ void k_loopale(const int* __restrict__ cnt, const float* __restrict__ sumattr,
                          const float* __restrict__ weatt,
                          float* __restrict__ loop1, float* __restrict__ loop2){
  int n = blockIdx.x*blockDim.x + threadIdx.x;
  if (n >= N_NODES) return;
  float inv = 1.f / fmaxf((float)cnt[n], 1.f);
  float l0 = 0.f, l1 = 0.f, l2 = 0.f;
  #pragma unroll
  for (int k = 0; k < EDIM; k++){
    float a = sumattr[n*EDIM + k] * inv;
    l0 += a*weatt[k*2 + 0];
    l1 += a*weatt[k*2 + 1];
    l2 += a*weatt[10 + k];
  }
  loop1[n*2 + 0] = l0; loop1[n*2 + 1] = l1; loop2[n] = l2;
}

// ---------------- K5: xh1 = x @ W1  ([N,128]@[128,128]) ----------------
#define G1_ROWS 32
__global__ void __launch_bounds__(128) k_gemm1(const float* __restrict__ x,
                                               const float* __restrict__ W,
                                               float* __restrict__ xh){
  __shared__ float xt[G1_ROWS][F_IN];
  int t = threadIdx.x;               // output column 0..127
  int r0 = blockIdx.x * G1_ROWS;
  for (int r = 0; r < G1_ROWS; r++){
    int row = r0 + r;
    xt[r][t] = (row < N_NODES) ? x[(size_t)row*F_IN + t] : 0.f;
  }
  __syncthreads();
  float acc[G1_ROWS];
  #pragma unroll
  for (int r = 0; r < G1_ROWS; r++) acc[r] = 0.f;
  for (int k = 0; k < F_IN; k += 4){
    float w0 = W[(k+0)*C1 + t], w1 = W[(k+1)*C1 + t];
    float w2 = W[(k+2)*C1 + t], w3 = W[(k+3)*C1 + t];
    #pragma unroll
    for (int r = 0; r < G1_ROWS; r++){
      float4 xv = *(const float4*)&xt[r][k];
      acc[r] += xv.x*w0 + xv.y*w1 + xv.z*w2 + xv.w*w3;
    }
  }
  for (int r = 0; r < G1_ROWS; r++){
    int row = r0 + r;
    if (row < N_NODES) xh[(size_t)row*C1 + t] = acc[r];
  }
}

// ---------------- K6: per-node attention scalars layer 1 (wave per node) ----------------
__global__ void k_att1(const float* __restrict__ xh, const float* __restrict__ a_src,
                       const float* __restrict__ a_dst,
                       float* __restrict__ as_o, float* __restrict__ ad_o){
  int node = blockIdx.x * (blockDim.x >> 6) + (threadIdx.x >> 6);
  int lane = threadIdx.x & 63;
  if (node >= N_NODES) return;
  float x0 = xh[(size_t)node*C1 + lane];
  float x1 = xh[(size_t)node*C1 + 64 + lane];
  float s0 = x0*a_src[lane],     s1 = x1*a_src[64 + lane];
  float d0 = x0*a_dst[lane],     d1 = x1*a_dst[64 + lane];
  for (int off = 1; off < 64; off <<= 1){
    s0 += __shfl_xor(s0, off); s1 += __shfl_xor(s1, off);
    d0 += __shfl_xor(d0, off); d1 += __shfl_xor(d1, off);
  }
  if (lane == 0){
    as_o[node*2+0] = s0; as_o[node*2+1] = s1;
    ad_o[node*2+0] = d0; ad_o[node*2+1] = d1;
  }
}

// ---------------- K7: layer-1 aggregation (block=128 per dst node) ----------------
__global__ void __launch_bounds__(128) k_agg1(const float* __restrict__ xh,
    const int* __restrict__ rowptr, const int* __restrict__ colsrc,
    const float* __restrict__ ale1, const float* __restrict__ as1,
    const float* __restrict__ ad1, const float* __restrict__ loop1,
    const float* __restrict__ b1, float* __restrict__ h1){
  int n = blockIdx.x;
  int t = threadIdx.x;
  int beg = rowptr[n], end = rowptr[n+1];
  float ad0 = ad1[n*2+0], adv1 = ad1[n*2+1];
  float sl0 = lrelu(as1[n*2+0] + ad0  + loop1[n*2+0]);
  float sl1 = lrelu(as1[n*2+1] + adv1 + loop1[n*2+1]);
  // phase A: online softmax denominators (both heads)
  float m0 = -INFINITY, s0 = 0.f, m1 = -INFINITY, s1 = 0.f;
  if (t == 0){ m0 = sl0; s0 = 1.f; m1 = sl1; s1 = 1.f; }
  for (int j = beg + t; j < end; j += 128){
    int s = colsrc[j];
    float2 a  = *(const float2*)&as1[s*2];
    float2 el = *(const float2*)&ale1[(size_t)j*2];
    sm_add(m0, s0, lrelu(a.x + ad0  + el.x));
    sm_add(m1, s1, lrelu(a.y + adv1 + el.y));
  }
  for (int off = 1; off < 64; off <<= 1){
    float mo0 = __shfl_xor(m0, off), so0 = __shfl_xor(s0, off);
    float mo1 = __shfl_xor(m1, off), so1 = __shfl_xor(s1, off);
    sm_merge(m0, s0, mo0, so0);
    sm_merge(m1, s1, mo1, so1);
  }
  __shared__ float mW[2][2], sW[2][2];
  int w = t >> 6;
  if ((t & 63) == 0){ mW[w][0] = m0; sW[w][0] = s0; mW[w][1] = m1; sW[w][1] = s1; }
  __syncthreads();
  float M0 = mW[0][0], S0 = sW[0][0], M1 = mW[0][1], S1 = sW[0][1];
  sm_merge(M0, S0, mW[1][0], sW[1][0]);
  sm_merge(M1, S1, mW[1][1], sW[1][1]);
  // phase B: weighted gather of xh[src] rows
  __shared__ int   sLs[64];
  __shared__ float e0L[64], e1L[64];
  float acc = 0.f;
  for (int base = beg; base < end; base += 64){
    int c = min(64, end - base);
    __syncthreads();
    if (t < c){
      int j = base + t; int s = colsrc[j];
      float2 a  = *(const float2*)&as1[s*2];
      float2 el = *(const float2*)&ale1[(size_t)j*2];
      sLs[t] = s;
      e0L[t] = expf(lrelu(a.x + ad0  + el.x) - M0);
      e1L[t] = expf(lrelu(a.y + adv1 + el.y) - M1);
    }
    __syncthreads();
    for (int k = 0; k < c; k++){
      float ex = (t < 64) ? e0L[k] : e1L[k];
      acc += ex * xh[(size_t)sLs[k]*C1 + t];
    }
  }
  float exs = expf(((t < 64) ? sl0 : sl1) - ((t < 64) ? M0 : M1));
  acc += exs * xh[(size_t)n*C1 + t];
  float den = ((t < 64) ? S0 : S1) + 1e-16f;
  float v = acc / den + b1[t];
  h1[(size_t)n*C1 + t] = v > 0.f ? v : expm1f(v);   // ELU
}

// ---------------- K8: xh2 = h1 @ W2 ([N,128]@[128,40]) ----------------
#define G2_ROWS 6
__global__ void __launch_bounds__(256) k_gemm2(const float* __restrict__ h1,
                                               const float* __restrict__ W2,
                                               float* __restrict__ xh2){
  __shared__ float wt[F_IN*OUT_C];
  __shared__ float xt[G2_ROWS][F_IN];
  int t = threadIdx.x;
  for (int i = t; i < F_IN*OUT_C; i += 256) wt[i] = W2[i];
  int r0 = blockIdx.x * G2_ROWS;
  for (int i = t; i < G2_ROWS*F_IN; i += 256){
    int r = i >> 7, c = i & 127;
    int row = r0 + r;
    xt[r][c] = (row < N_NODES) ? h1[(size_t)row*F_IN + c] : 0.f;
  }
  __syncthreads();
  if (t < G2_ROWS*OUT_C){
    int lr = t / OUT_C, c = t % OUT_C;
    int row = r0 + lr;
    if (row < N_NODES){
      float acc = 0.f;
      for (int k = 0; k < F_IN; k += 4){
        float4 xv = *(const float4*)&xt[lr][k];
        acc += xv.x*wt[(k+0)*OUT_C + c] + xv.y*wt[(k+1)*OUT_C + c]
             + xv.z*wt[(k+2)*OUT_C + c] + xv.w*wt[(k+3)*OUT_C + c];
      }
      xh2[(size_t)row*OUT_C + c] = acc;
    }
  }
}

// ---------------- K9: per-node attention scalars layer 2 ----------------
__global__ void k_att2(const float* __restrict__ xh2, const float* __restrict__ a_src,
                       const float* __restrict__ a_dst,
                       float* __restrict__ as_o, float* __restrict__ ad_o){
  int node = blockIdx.x * (blockDim.x >> 6) + (threadIdx.x >> 6);
  int lane = threadIdx.x & 63;
  if (node >= N_NODES) return;
  float v = (lane < OUT_C) ? xh2[(size_t)node*OUT_C + lane] : 0.f;
  float s = (lane < OUT_C) ? v*a_src[lane] : 0.f;
  float d = (lane < OUT_C) ? v*a_dst[lane] : 0.f;
  for (int off = 1; off < 64; off <<= 1){
    s += __shfl_xor(s, off);
    d += __shfl_xor(d, off);
  }
  if (lane == 0){ as_o[node] = s; ad_o[node] = d; }
}

// ---------------- K10: layer-2 aggregation + log_softmax (wave per node) ----------------
__global__ void __launch_bounds__(64) k_agg2(const float* __restrict__ xh2,
    const int* __restrict__ rowptr, const int* __restrict__ colsrc,
    const float* __restrict__ ale2, const float* __restrict__ as2,
    const float* __restrict__ ad2, const float* __restrict__ loop2,
    const float* __restrict__ b2, float* __restrict__ out){
  int n = blockIdx.x;
  int t = threadIdx.x;
  int beg = rowptr[n], end = rowptr[n+1];
  float adv = ad2[n];
  float sl = lrelu(as2[n] + adv + loop2[n]);
  float m = -INFINITY, ss = 0.f;
  if (t == 0){ m = sl; ss = 1.f; }
  for (int j = beg + t; j < end; j += 64){
    int s = colsrc[j];
    sm_add(m, ss, lrelu(as2[s] + adv + ale2[j]));
  }
  for (int off = 1; off < 64; off <<= 1){
    float mo = __shfl_xor(m, off), so = __shfl_xor(ss, off);
    sm_merge(m, ss, mo, so);
  }
  __shared__ int   sLs[64];
  __shared__ float exL[64];
  float acc = 0.f;
  for (int base = beg; base < end; base += 64){
    int c = min(64, end - base);
    __syncthreads();
    if (t < c){
      int j = base + t; int s = colsrc[j];
      sLs[t] = s;
      exL[t] = expf(lrelu(as2[s] + adv + ale2[j]) - m);
    }
    __syncthreads();
    if (t < OUT_C){
      for (int k = 0; k < c; k++) acc += exL[k] * xh2[(size_t)sLs[k]*OUT_C + t];
    }
  }
  float o;
  if (t < OUT_C){
    acc += expf(sl - m) * xh2[(size_t)n*OUT_C + t];
    o = acc / (ss + 1e-16f) + b2[t];
  } else {
    o = -INFINITY;
  }
  // log_softmax over the 40 columns
  float mm = o;
  for (int off = 1; off < 64; off <<= 1) mm = fmaxf(mm, __shfl_xor(mm, off));
  float e = (t < OUT_C) ? expf(o - mm) : 0.f;
  for (int off = 1; off < 64; off <<= 1) e += __shfl_xor(e, off);
  if (t < OUT_C) out[(size_t)n*OUT_C + t] = o - mm - logf(e);
}

// ---------------- host launcher ----------------
extern "C" void kernel_launch(void* const* d_in, const int* in_sizes, int n_in,
                              void* d_out, int out_size, void* d_ws, size_t ws_size,
                              hipStream_t stream){
  const float* x        = (const float*)d_in[0];
  const int*   ei       = (const int*)  d_in[1];
  const float* eattr    = (const float*)d_in[2];
  const float* W1       = (const float*)d_in[3];
  const float* att_src1 = (const float*)d_in[4];
  const float* att_dst1 = (const float*)d_in[5];
  const float* We1      = (const float*)d_in[6];
  const float* att_e1   = (const float*)d_in[7];
  const float* b1       = (const float*)d_in[8];
  const float* W2       = (const float*)d_in[9];
  const float* att_src2 = (const float*)d_in[10];
  const float* att_dst2 = (const float*)d_in[11];
  const float* We2      = (const float*)d_in[12];
  const float* att_e2   = (const float*)d_in[13];
  const float* b2       = (const float*)d_in[14];
  const int* src = ei;
  const int* dst = ei + N_EDGES;

  float* wsf    = (float*)d_ws;
  int*   cnt     = (int*)(wsf + O_CNT);
  int*   fill    = (int*)(wsf + O_FILL);
  float* sumattr = wsf + O_SUMATTR;
  int*   rowptr  = (int*)(wsf + O_ROWPTR);
  int*   colsrc  = (int*)(wsf + O_COLSRC);
  float* ale1    = wsf + O_ALE1;
  float* ale2    = wsf + O_ALE2;
  float* weatt   = wsf + O_WEATT;
  float* loop1   = wsf + O_LOOP1;
  float* loop2   = wsf + O_LOOP2;
  float* xh1     = wsf + O_XH1;
  float* as1     = wsf + O_AS1;
  float* ad1     = wsf + O_AD1;
  float* h1      = wsf + O_H1;
  float* xh2     = wsf + O_XH2;
  float* as2     = wsf + O_AS2;
  float* ad2     = wsf + O_AD2;
  float* out     = (float*)d_out;

  hipMemsetAsync(wsf + O_CNT, 0, O_ZERO_END*sizeof(float), stream);

  const int EB = (N_EDGES + 255) / 256;

  k_weatt  <<<1, 64, 0, stream>>>(We1, att_e1, We2, att_e2, weatt);
  k_count  <<<EB, 256, 0, stream>>>(dst, eattr, cnt, sumattr);
  k_scan   <<<1, 1024, 0, stream>>>(cnt, rowptr);
  k_scatter<<<EB, 256, 0, stream>>>(src, dst, eattr, rowptr, fill, colsrc, weatt, ale1, ale2);
  k_loopale<<<(N_NODES + 255)/256, 256, 0, stream>>>(cnt, sumattr, weatt, loop1, loop2);

  k_gemm1  <<<(N_NODES + G1_ROWS - 1)/G1_ROWS, 128, 0, stream>>>(x, W1, xh1);
  k_att1   <<<(N_NODES + 3)/4, 256, 0, stream>>>(xh1, att_src1, att_dst1, as1, ad1);
  k_agg1   <<<N_NODES, 128, 0, stream>>>(xh1, rowptr, colsrc, ale1, as1, ad1, loop1, b1, h1);

  k_gemm2  <<<(N_NODES + G2_ROWS - 1)/G2_ROWS, 256, 0, stream>>>(h1, W2, xh2);
  k_att2   <<<(N_NODES + 3)/4, 256, 0, stream>>>(xh2, att_src2, att_dst2, as2, ad2);
  k_agg2   <<<N_NODES, 64, 0, stream>>>(xh2, rowptr, colsrc, ale2, as2, ad2, loop2, b2, out);
}

// Round 2
// 503.451 us; speedup vs baseline: 1.3675x; 1.3675x over previous
//
#include <hip/hip_runtime.h>
#include <math.h>

#define N_NODES 50000
#define N_EDGES 800000
#define F_IN    128
#define HID     64
#define HEADS   2
#define C1      128   // HEADS*HID
#define OUT_C   40
#define EDIM    5
#define NEG_SLOPE 0.2f

// ---------------- workspace layout (element offsets, 4B units) ----------------
constexpr size_t pad64(size_t n){ return (n + 63) / 64 * 64; }
constexpr size_t O_CNT      = 0;
constexpr size_t O_FILL     = O_CNT      + pad64(N_NODES);
constexpr size_t O_ZERO_END = O_FILL     + pad64(N_NODES);
constexpr size_t O_ROWPTR   = O_ZERO_END;
constexpr size_t O_COLSRC   = O_ROWPTR   + pad64(N_NODES+1);
constexpr size_t O_ALE1     = O_COLSRC   + pad64(N_EDGES);
constexpr size_t O_ALE2     = O_ALE1     + pad64((size_t)N_EDGES*2);
constexpr size_t O_WEATT    = O_ALE2     + pad64(N_EDGES);
constexpr size_t O_XH1      = O_WEATT    + 64;
constexpr size_t O_AS1      = O_XH1      + pad64((size_t)N_NODES*C1);
constexpr size_t O_AD1      = O_AS1      + pad64((size_t)N_NODES*2);
constexpr size_t O_H1       = O_AD1      + pad64((size_t)N_NODES*2);
constexpr size_t O_XH2      = O_H1       + pad64((size_t)N_NODES*C1);
constexpr size_t O_AS2      = O_XH2      + pad64((size_t)N_NODES*OUT_C);
constexpr size_t O_AD2      = O_AS2      + pad64(N_NODES);

__device__ __forceinline__ float lrelu(float v){ return v >= 0.f ? v : NEG_SLOPE*v; }

// online-softmax: add one logit with weight 1
__device__ __forceinline__ void sm_add(float& m, float& s, float l){
  if (l > m){ s = s*expf(m - l) + 1.f; m = l; }
  else      { s += expf(l - m); }
}
// merge two (max, sum) states; (mo,so) may be empty (so==0)
__device__ __forceinline__ void sm_merge(float& m, float& s, float mo, float so){
  if (so > 0.f){
    if (mo > m){ s = s*expf(m - mo) + so; m = mo; }
    else       { s += so*expf(mo - m); }
  }
}

// ---------------- K0: tiny attention-projection matrices ----------------
// weatt[k*2+h]  = sum_c We1[k,h*64+c]*att_e1[h,c]   (k<5,h<2)
// weatt[10+k]   = sum_c We2[k,c]*att_e2[c]
__global__ void k_weatt(const float* __restrict__ We1, const float* __restrict__ ae1,
                        const float* __restrict__ We2, const float* __restrict__ ae2,
                        float* __restrict__ weatt){
  int t = threadIdx.x;
  if (t < 10){
    int k = t >> 1, h = t & 1;
    float s = 0.f;
    for (int c = 0; c < HID; c++) s += We1[k*C1 + h*HID + c] * ae1[h*HID + c];
    weatt[k*2 + h] = s;
  } else if (t < 15){
    int k = t - 10;
    float s = 0.f;
    for (int c = 0; c < OUT_C; c++) s += We2[k*OUT_C + c] * ae2[c];
    weatt[10 + k] = s;
  }
}

// ---------------- K1: in-degree only (int atomics, L2-resident counters) ----------------
__global__ void k_count(const int* __restrict__ dst, int* __restrict__ cnt){
  int e = blockIdx.x*blockDim.x + threadIdx.x;
  if (e >= N_EDGES) return;
  atomicAdd(&cnt[dst[e]], 1);
}

// ---------------- K2: exclusive scan of cnt -> rowptr ----------------
__global__ void __launch_bounds__(1024) k_scan(const int* __restrict__ cnt, int* __restrict__ rowptr){
  __shared__ int part[1024];
  int t = threadIdx.x;
  const int CH = (N_NODES + 1023) / 1024;
  int base = t * CH;
  int s = 0;
  for (int i = 0; i < CH; i++){ int idx = base + i; if (idx < N_NODES) s += cnt[idx]; }
  part[t] = s; __syncthreads();
  for (int off = 1; off < 1024; off <<= 1){
    int v = (t >= off) ? part[t - off] : 0;
    __syncthreads();
    part[t] += v;
    __syncthreads();
  }
  int run = (t == 0) ? 0 : part[t - 1];
  for (int i = 0; i < CH; i++){
    int idx = base + i;
    if (idx < N_NODES){ rowptr[idx] = run; run += cnt[idx]; }
  }
  if (t == 1023) rowptr[N_NODES] = part[1023];
}

// ---------------- K3: scatter edges into CSR; precompute per-edge attn-attr dots ----------------
__global__ void k_scatter(const int* __restrict__ src, const int* __restrict__ dst,
                          const float* __restrict__ eattr, const int* __restrict__ rowptr,
                          int* __restrict__ fill, int* __restrict__ colsrc,
                          const float* __restrict__ weatt,
                          float* __restrict__ ale1, float* __restrict__ ale2){
  int e = blockIdx.x*blockDim.x + threadIdx.x;
  if (e >= N_EDGES) return;
  int d = dst[e];
  int pos = rowptr[d] + atomicAdd(&fill[d], 1);
  colsrc[pos] = src[e];
  float a[EDIM];
  #pragma unroll
  for (int k = 0; k < EDIM; k++) a[k] = eattr[e*EDIM + k];
  float l0 = 0.f, l1 = 0.f, l2 = 0.f;
  #pragma unroll
  for (int k = 0; k < EDIM; k++){
    l0 += a[k]*weatt[k*2 + 0];
    l1 += a[k]*weatt[k*2 + 1];
    l2 += a[k]*weatt[10 + k];
  }
  ale1[pos*2 + 0] = l0; ale1[pos*2 + 1] = l1; ale2[pos] = l2;
}

// ---------------- K5: xh1 = x @ W1  ([N,128]@[128,128]) ----------------
#define G1_ROWS 32
__global__ void __launch_bounds__(128) k_gemm1(const float* __restrict__ x,
                                               const float* __restrict__ W,
                                               float* __restrict__ xh){
  __shared__ float xt[G1_ROWS][F_IN];
  int t = threadIdx.x;               // output column 0..127
  int r0 = blockIdx.x * G1_ROWS;
  for (int r = 0; r < G1_ROWS; r++){
    int row = r0 + r;
    xt[r][t] = (row < N_NODES) ? x[(size_t)row*F_IN + t] : 0.f;
  }
  __syncthreads();
  float acc[G1_ROWS];
  #pragma unroll
  for (int r = 0; r < G1_ROWS; r++) acc[r] = 0.f;
  for (int k = 0; k < F_IN; k += 4){
    float w0 = W[(k+0)*C1 + t], w1 = W[(k+1)*C1 + t];
    float w2 = W[(k+2)*C1 + t], w3 = W[(k+3)*C1 + t];
    #pragma unroll
    for (int r = 0; r < G1_ROWS; r++){
      float4 xv = *(const float4*)&xt[r][k];
      acc[r] += xv.x*w0 + xv.y*w1 + xv.z*w2 + xv.w*w3;
    }
  }
  for (int r = 0; r < G1_ROWS; r++){
    int row = r0 + r;
    if (row < N_NODES) xh[(size_t)row*C1 + t] = acc[r];
  }
}

// ---------------- K6: per-node attention scalars layer 1 (wave per node) ----------------
__global__ void k_att1(const float* __restrict__ xh, const float* __restrict__ a_src,
                       const float* __restrict__ a_dst,
                       float* __restrict__ as_o, float* __restrict__ ad_o){
  int node = blockIdx.x * (blockDim.x >> 6) + (threadIdx.x >> 6);
  int lane = threadIdx.x & 63;
  if (node >= N_NODES) return;
  float x0 = xh[(size_t)node*C1 + lane];
  float x1 = xh[(size_t)node*C1 + 64 + lane];
  float s0 = x0*a_src[lane],     s1 = x1*a_src[64 + lane];
  float d0 = x0*a_dst[lane],     d1 = x1*a_dst[64 + lane];
  for (int off = 1; off < 64; off <<= 1){
    s0 += __shfl_xor(s0, off); s1 += __shfl_xor(s1, off);
    d0 += __shfl_xor(d0, off); d1 += __shfl_xor(d1, off);
  }
  if (lane == 0){
    as_o[node*2+0] = s0; as_o[node*2+1] = s1;
    ad_o[node*2+0] = d0; ad_o[node*2+1] = d1;
  }
}

// ---------------- K7: layer-1 aggregation (block=128 per dst node) ----------------
// self-loop attr dot = (sum of ale1 over in-edges)/deg  (linearity of the dot)
__global__ void __launch_bounds__(128) k_agg1(const float* __restrict__ xh,
    const int* __restrict__ rowptr, const int* __restrict__ colsrc,
    const float* __restrict__ ale1, const float* __restrict__ as1,
    const float* __restrict__ ad1,
    const float* __restrict__ b1, float* __restrict__ h1){
  int n = blockIdx.x;
  int t = threadIdx.x;
  int beg = rowptr[n], end = rowptr[n+1];
  float ad0 = ad1[n*2+0], adv1 = ad1[n*2+1];
  // phase A: online softmax denominators (both heads) + sum of ale for self-loop
  float m0 = -INFINITY, s0 = 0.f, m1 = -INFINITY, s1 = 0.f;
  float la0 = 0.f, la1 = 0.f;
  for (int j = beg + t; j < end; j += 128){
    int s = colsrc[j];
    float2 a  = *(const float2*)&as1[s*2];
    float2 el = *(const float2*)&ale1[(size_t)j*2];
    la0 += el.x; la1 += el.y;
    sm_add(m0, s0, lrelu(a.x + ad0  + el.x));
    sm_add(m1, s1, lrelu(a.y + adv1 + el.y));
  }
  for (int off = 1; off < 64; off <<= 1){
    float mo0 = __shfl_xor(m0, off), so0 = __shfl_xor(s0, off);
    float mo1 = __shfl_xor(m1, off), so1 = __shfl_xor(s1, off);
    sm_merge(m0, s0, mo0, so0);
    sm_merge(m1, s1, mo1, so1);
    la0 += __shfl_xor(la0, off); la1 += __shfl_xor(la1, off);
  }
  __shared__ float mW[2][2], sW[2][2], laW[2][2];
  int w = t >> 6;
  if ((t & 63) == 0){
    mW[w][0] = m0; sW[w][0] = s0; mW[w][1] = m1; sW[w][1] = s1;
    laW[w][0] = la0; laW[w][1] = la1;
  }
  __syncthreads();
  float M0 = mW[0][0], S0 = sW[0][0], M1 = mW[0][1], S1 = sW[0][1];
  sm_merge(M0, S0, mW[1][0], sW[1][0]);
  sm_merge(M1, S1, mW[1][1], sW[1][1]);
  int deg = end - beg;
  float inv = 1.f / fmaxf((float)deg, 1.f);
  float sl0 = lrelu(as1[n*2+0] + ad0  + (laW[0][0] + laW[1][0]) * inv);
  float sl1 = lrelu(as1[n*2+1] + adv1 + (laW[0][1] + laW[1][1]) * inv);
  sm_add(M0, S0, sl0);
  sm_add(M1, S1, sl1);
  // phase B: weighted gather of xh[src] rows
  __shared__ int   sLs[64];
  __shared__ float e0L[64], e1L[64];
  float acc = 0.f;
  for (int base = beg; base < end; base += 64){
    int c = min(64, end - base);
    __syncthreads();
    if (t < c){
      int j = base + t; int s = colsrc[j];
      float2 a  = *(const float2*)&as1[s*2];
      float2 el = *(const float2*)&ale1[(size_t)j*2];
      sLs[t] = s;
      e0L[t] = expf(lrelu(a.x + ad0  + el.x) - M0);
      e1L[t] = expf(lrelu(a.y + adv1 + el.y) - M1);
    }
    __syncthreads();
    for (int k = 0; k < c; k++){
      float ex = (t < 64) ? e0L[k] : e1L[k];
      acc += ex * xh[(size_t)sLs[k]*C1 + t];
    }
  }
  float exs = expf(((t < 64) ? sl0 : sl1) - ((t < 64) ? M0 : M1));
  acc += exs * xh[(size_t)n*C1 + t];
  float den = ((t < 64) ? S0 : S1) + 1e-16f;
  float v = acc / den + b1[t];
  h1[(size_t)n*C1 + t] = v > 0.f ? v : expm1f(v);   // ELU
}

// ---------------- K8: xh2 = h1 @ W2 ([N,128]@[128,40]) ----------------
#define G2_ROWS 6
__global__ void __launch_bounds__(256) k_gemm2(const float* __restrict__ h1,
                                               const float* __restrict__ W2,
                                               float* __restrict__ xh2){
  __shared__ float wt[F_IN*OUT_C];
  __shared__ float xt[G2_ROWS][F_IN];
  int t = threadIdx.x;
  for (int i = t; i < F_IN*OUT_C; i += 256) wt[i] = W2[i];
  int r0 = blockIdx.x * G2_ROWS;
  for (int i = t; i < G2_ROWS*F_IN; i += 256){
    int r = i >> 7, c = i & 127;
    int row = r0 + r;
    xt[r][c] = (row < N_NODES) ? h1[(size_t)row*F_IN + c] : 0.f;
  }
  __syncthreads();
  if (t < G2_ROWS*OUT_C){
    int lr = t / OUT_C, c = t % OUT_C;
    int row = r0 + lr;
    if (row < N_NODES){
      float acc = 0.f;
      for (int k = 0; k < F_IN; k += 4){
        float4 xv = *(const float4*)&xt[lr][k];
        acc += xv.x*wt[(k+0)*OUT_C + c] + xv.y*wt[(k+1)*OUT_C + c]
             + xv.z*wt[(k+2)*OUT_C + c] + xv.w*wt[(k+3)*OUT_C + c];
      }
      xh2[(size_t)row*OUT_C + c] = acc;
    }
  }
}

// ---------------- K9: per-node attention scalars layer 2 ----------------
__global__ void k_att2(const float* __restrict__ xh2, const float* __restrict__ a_src,
                       const float* __restrict__ a_dst,
                       float* __restrict__ as_o, float* __restrict__ ad_o){
  int node = blockIdx.x * (blockDim.x >> 6) + (threadIdx.x >> 6);
  int lane = threadIdx.x & 63;
  if (node >= N_NODES) return;
  float v = (lane < OUT_C) ? xh2[(size_t)node*OUT_C + lane] : 0.f;
  float s = (lane < OUT_C) ? v*a_src[lane] : 0.f;
  float d = (lane < OUT_C) ? v*a_dst[lane] : 0.f;
  for (int off = 1; off < 64; off <<= 1){
    s += __shfl_xor(s, off);
    d += __shfl_xor(d, off);
  }
  if (lane == 0){ as_o[node] = s; ad_o[node] = d; }
}

// ---------------- K10: layer-2 aggregation + log_softmax (wave per node) ----------------
__global__ void __launch_bounds__(64) k_agg2(const float* __restrict__ xh2,
    const int* __restrict__ rowptr, const int* __restrict__ colsrc,
    const float* __restrict__ ale2, const float* __restrict__ as2,
    const float* __restrict__ ad2,
    const float* __restrict__ b2, float* __restrict__ out){
  int n = blockIdx.x;
  int t = threadIdx.x;
  int beg = rowptr[n], end = rowptr[n+1];
  float adv = ad2[n];
  float m = -INFINITY, ss = 0.f, la = 0.f;
  for (int j = beg + t; j < end; j += 64){
    int s = colsrc[j];
    la += ale2[j];
    sm_add(m, ss, lrelu(as2[s] + adv + ale2[j]));
  }
  for (int off = 1; off < 64; off <<= 1){
    float mo = __shfl_xor(m, off), so = __shfl_xor(ss, off);
    sm_merge(m, ss, mo, so);
    la += __shfl_xor(la, off);
  }
  int deg = end - beg;
  float sl = lrelu(as2[n] + adv + la / fmaxf((float)deg, 1.f));
  sm_add(m, ss, sl);
  __shared__ int   sLs[64];
  __shared__ float exL[64];
  float acc = 0.f;
  for (int base = beg; base < end; base += 64){
    int c = min(64, end - base);
    __syncthreads();
    if (t < c){
      int j = base + t; int s = colsrc[j];
      sLs[t] = s;
      exL[t] = expf(lrelu(as2[s] + adv + ale2[j]) - m);
    }
    __syncthreads();
    if (t < OUT_C){
      for (int k = 0; k < c; k++) acc += exL[k] * xh2[(size_t)sLs[k]*OUT_C + t];
    }
  }
  float o;
  if (t < OUT_C){
    acc += expf(sl - m) * xh2[(size_t)n*OUT_C + t];
    o = acc / (ss + 1e-16f) + b2[t];
  } else {
    o = -INFINITY;
  }
  // log_softmax over the 40 columns
  float mm = o;
  for (int off = 1; off < 64; off <<= 1) mm = fmaxf(mm, __shfl_xor(mm, off));
  float e = (t < OUT_C) ? expf(o - mm) : 0.f;
  for (int off = 1; off < 64; off <<= 1) e += __shfl_xor(e, off);
  if (t < OUT_C) out[(size_t)n*OUT_C + t] = o - mm - logf(e);
}

// ---------------- host launcher ----------------
extern "C" void kernel_launch(void* const* d_in, const int* in_sizes, int n_in,
                              void* d_out, int out_size, void* d_ws, size_t ws_size,
                              hipStream_t stream){
  const float* x        = (const float*)d_in[0];
  const int*   ei       = (const int*)  d_in[1];
  const float* eattr    = (const float*)d_in[2];
  const float* W1       = (const float*)d_in[3];
  const float* att_src1 = (const float*)d_in[4];
  const float* att_dst1 = (const float*)d_in[5];
  const float* We1      = (const float*)d_in[6];
  const float* att_e1   = (const float*)d_in[7];
  const float* b1       = (const float*)d_in[8];
  const float* W2       = (const float*)d_in[9];
  const float* att_src2 = (const float*)d_in[10];
  const float* att_dst2 = (const float*)d_in[11];
  const float* We2      = (const float*)d_in[12];
  const float* att_e2   = (const float*)d_in[13];
  const float* b2       = (const float*)d_in[14];
  const int* src = ei;
  const int* dst = ei + N_EDGES;

  float* wsf    = (float*)d_ws;
  int*   cnt     = (int*)(wsf + O_CNT);
  int*   fill    = (int*)(wsf + O_FILL);
  int*   rowptr  = (int*)(wsf + O_ROWPTR);
  int*   colsrc  = (int*)(wsf + O_COLSRC);
  float* ale1    = wsf + O_ALE1;
  float* ale2    = wsf + O_ALE2;
  float* weatt   = wsf + O_WEATT;
  float* xh1     = wsf + O_XH1;
  float* as1     = wsf + O_AS1;
  float* ad1     = wsf + O_AD1;
  float* h1      = wsf + O_H1;
  float* xh2     = wsf + O_XH2;
  float* as2     = wsf + O_AS2;
  float* ad2     = wsf + O_AD2;
  float* out     = (float*)d_out;

  hipMemsetAsync(wsf + O_CNT, 0, O_ZERO_END*sizeof(float), stream);

  const int EB = (N_EDGES + 255) / 256;

  k_weatt  <<<1, 64, 0, stream>>>(We1, att_e1, We2, att_e2, weatt);
  k_count  <<<EB, 256, 0, stream>>>(dst, cnt);
  k_scan   <<<1, 1024, 0, stream>>>(cnt, rowptr);
  k_scatter<<<EB, 256, 0, stream>>>(src, dst, eattr, rowptr, fill, colsrc, weatt, ale1, ale2);

  k_gemm1  <<<(N_NODES + G1_ROWS - 1)/G1_ROWS, 128, 0, stream>>>(x, W1, xh1);
  k_att1   <<<(N_NODES + 3)/4, 256, 0, stream>>>(xh1, att_src1, att_dst1, as1, ad1);
  k_agg1   <<<N_NODES, 128, 0, stream>>>(xh1, rowptr, colsrc, ale1, as1, ad1, b1, h1);

  k_gemm2  <<<(N_NODES + G2_ROWS - 1)/G2_ROWS, 256, 0, stream>>>(h1, W2, xh2);
  k_att2   <<<(N_NODES + 3)/4, 256, 0, stream>>>(xh2, att_src2, att_dst2, as2, ad2);
  k_agg2   <<<N_NODES, 64, 0, stream>>>(xh2, rowptr, colsrc, ale2, as2, ad2, b2, out);
}

// Round 3
// 464.839 us; speedup vs baseline: 1.4811x; 1.0831x over previous
//
#include <hip/hip_runtime.h>
#include <math.h>

#define N_NODES 50000
#define N_EDGES 800000
#define F_IN    128
#define HID     64
#define HEADS   2
#define C1      128   // HEADS*HID
#define OUT_C   40
#define EDIM    5
#define NEG_SLOPE 0.2f
#define CAP1    768   // LDS edge cache, layer-1 agg (Poisson(16) => never exceeded; fallback kept)
#define CAP2    512   // LDS edge cache, layer-2 agg

// ---------------- workspace layout (element offsets, 4B units) ----------------
constexpr size_t pad64(size_t n){ return (n + 63) / 64 * 64; }
constexpr size_t O_CNT      = 0;
constexpr size_t O_FILL     = O_CNT      + pad64(N_NODES);
constexpr size_t O_ZERO_END = O_FILL     + pad64(N_NODES);
constexpr size_t O_ROWPTR   = O_ZERO_END;
constexpr size_t O_EREC     = O_ROWPTR   + pad64(N_NODES+1);   // float4 per edge {src, l1h0, l1h1, l2}
constexpr size_t O_WEATT    = O_EREC     + pad64((size_t)N_EDGES*4);
constexpr size_t O_XH1      = O_WEATT    + 64;
constexpr size_t O_AS1      = O_XH1      + pad64((size_t)N_NODES*C1);
constexpr size_t O_AD1      = O_AS1      + pad64((size_t)N_NODES*2);
constexpr size_t O_H1       = O_AD1      + pad64((size_t)N_NODES*2);
constexpr size_t O_XH2      = O_H1       + pad64((size_t)N_NODES*C1);
constexpr size_t O_AS2      = O_XH2      + pad64((size_t)N_NODES*OUT_C);
constexpr size_t O_AD2      = O_AS2      + pad64(N_NODES);

__device__ __forceinline__ float lrelu(float v){ return v >= 0.f ? v : NEG_SLOPE*v; }

// ---------------- K0: tiny attention-projection matrices ----------------
__global__ void k_weatt(const float* __restrict__ We1, const float* __restrict__ ae1,
                        const float* __restrict__ We2, const float* __restrict__ ae2,
                        float* __restrict__ weatt){
  int t = threadIdx.x;
  if (t < 10){
    int k = t >> 1, h = t & 1;
    float s = 0.f;
    for (int c = 0; c < HID; c++) s += We1[k*C1 + h*HID + c] * ae1[h*HID + c];
    weatt[k*2 + h] = s;
  } else if (t < 15){
    int k = t - 10;
    float s = 0.f;
    for (int c = 0; c < OUT_C; c++) s += We2[k*OUT_C + c] * ae2[c];
    weatt[10 + k] = s;
  }
}

// ---------------- K1: in-degree (int atomics, L2-resident) ----------------
__global__ void k_count(const int* __restrict__ dst, int* __restrict__ cnt){
  int e = blockIdx.x*blockDim.x + threadIdx.x;
  if (e >= N_EDGES) return;
  atomicAdd(&cnt[dst[e]], 1);
}

// ---------------- K2: exclusive scan of cnt -> rowptr ----------------
__global__ void __launch_bounds__(1024) k_scan(const int* __restrict__ cnt, int* __restrict__ rowptr){
  __shared__ int part[1024];
  int t = threadIdx.x;
  const int CH = (N_NODES + 1023) / 1024;
  int base = t * CH;
  int s = 0;
  for (int i = 0; i < CH; i++){ int idx = base + i; if (idx < N_NODES) s += cnt[idx]; }
  part[t] = s; __syncthreads();
  for (int off = 1; off < 1024; off <<= 1){
    int v = (t >= off) ? part[t - off] : 0;
    __syncthreads();
    part[t] += v;
    __syncthreads();
  }
  int run = (t == 0) ? 0 : part[t - 1];
  for (int i = 0; i < CH; i++){
    int idx = base + i;
    if (idx < N_NODES){ rowptr[idx] = run; run += cnt[idx]; }
  }
  if (t == 1023) rowptr[N_NODES] = part[1023];
}

// ---------------- K3: scatter edges into CSR as interleaved float4 records ----------------
__global__ void k_scatter(const int* __restrict__ src, const int* __restrict__ dst,
                          const float* __restrict__ eattr, const int* __restrict__ rowptr,
                          int* __restrict__ fill, const float* __restrict__ weatt,
                          float4* __restrict__ erec){
  int e = blockIdx.x*blockDim.x + threadIdx.x;
  if (e >= N_EDGES) return;
  int d = dst[e];
  int pos = rowptr[d] + atomicAdd(&fill[d], 1);
  float a[EDIM];
  #pragma unroll
  for (int k = 0; k < EDIM; k++) a[k] = eattr[e*EDIM + k];
  float l0 = 0.f, l1 = 0.f, l2 = 0.f;
  #pragma unroll
  for (int k = 0; k < EDIM; k++){
    l0 += a[k]*weatt[k*2 + 0];
    l1 += a[k]*weatt[k*2 + 1];
    l2 += a[k]*weatt[10 + k];
  }
  erec[pos] = make_float4(__int_as_float(src[e]), l0, l1, l2);
}

// ---------------- K5: xh1 = x @ W1  ([N,128]@[128,128]) ----------------
#define G1_ROWS 32
__global__ void __launch_bounds__(128) k_gemm1(const float* __restrict__ x,
                                               const float* __restrict__ W,
                                               float* __restrict__ xh){
  __shared__ float xt[G1_ROWS][F_IN];
  int t = threadIdx.x;
  int r0 = blockIdx.x * G1_ROWS;
  for (int r = 0; r < G1_ROWS; r++){
    int row = r0 + r;
    xt[r][t] = (row < N_NODES) ? x[(size_t)row*F_IN + t] : 0.f;
  }
  __syncthreads();
  float acc[G1_ROWS];
  #pragma unroll
  for (int r = 0; r < G1_ROWS; r++) acc[r] = 0.f;
  for (int k = 0; k < F_IN; k += 4){
    float w0 = W[(k+0)*C1 + t], w1 = W[(k+1)*C1 + t];
    float w2 = W[(k+2)*C1 + t], w3 = W[(k+3)*C1 + t];
    #pragma unroll
    for (int r = 0; r < G1_ROWS; r++){
      float4 xv = *(const float4*)&xt[r][k];
      acc[r] += xv.x*w0 + xv.y*w1 + xv.z*w2 + xv.w*w3;
    }
  }
  for (int r = 0; r < G1_ROWS; r++){
    int row = r0 + r;
    if (row < N_NODES) xh[(size_t)row*C1 + t] = acc[r];
  }
}

// ---------------- K6: per-node attention scalars layer 1 (wave per node) ----------------
__global__ void k_att1(const float* __restrict__ xh, const float* __restrict__ a_src,
                       const float* __restrict__ a_dst,
                       float* __restrict__ as_o, float* __restrict__ ad_o){
  int node = blockIdx.x * (blockDim.x >> 6) + (threadIdx.x >> 6);
  int lane = threadIdx.x & 63;
  if (node >= N_NODES) return;
  float x0 = xh[(size_t)node*C1 + lane];
  float x1 = xh[(size_t)node*C1 + 64 + lane];
  float s0 = x0*a_src[lane],     s1 = x1*a_src[64 + lane];
  float d0 = x0*a_dst[lane],     d1 = x1*a_dst[64 + lane];
  for (int off = 1; off < 64; off <<= 1){
    s0 += __shfl_xor(s0, off); s1 += __shfl_xor(s1, off);
    d0 += __shfl_xor(d0, off); d1 += __shfl_xor(d1, off);
  }
  if (lane == 0){
    as_o[node*2+0] = s0; as_o[node*2+1] = s1;
    ad_o[node*2+0] = d0; ad_o[node*2+1] = d1;
  }
}

// ---------------- K7: layer-1 aggregation, logit-cached in LDS ----------------
__global__ void __launch_bounds__(128) k_agg1(const float* __restrict__ xh,
    const int* __restrict__ rowptr, const float4* __restrict__ erec,
    const float* __restrict__ as1, const float* __restrict__ ad1,
    const float* __restrict__ b1, float* __restrict__ h1){
  __shared__ int   srcA[CAP1];
  __shared__ float e0A[CAP1], e1A[CAP1];
  __shared__ float mW[2][2], laW[2][2], sW[2][2];
  int n = blockIdx.x, t = threadIdx.x;
  int w = t >> 6, lane = t & 63;
  int beg = rowptr[n], end = rowptr[n+1];
  int deg = end - beg;
  float ad0 = ad1[n*2+0], adv1 = ad1[n*2+1];
  float inv = 1.f / fmaxf((float)deg, 1.f);
  float M0, M1, sl0, sl1, es0, es1, S0, S1;
  float acc = 0.f;
  const float* eSel = (t < 64) ? e0A : e1A;

  if (deg <= CAP1){
    // pass A: logits -> LDS, plain max + ale-sum reduce
    float m0 = -INFINITY, m1 = -INFINITY, la0 = 0.f, la1 = 0.f;
    for (int i = t; i < deg; i += 128){
      float4 r = erec[(size_t)beg + i];
      int s = __float_as_int(r.x);
      float2 a = *(const float2*)&as1[s*2];
      float lg0 = lrelu(a.x + ad0  + r.y);
      float lg1 = lrelu(a.y + adv1 + r.z);
      srcA[i] = s * C1;
      e0A[i] = lg0; e1A[i] = lg1;
      m0 = fmaxf(m0, lg0); m1 = fmaxf(m1, lg1);
      la0 += r.y; la1 += r.z;
    }
    for (int off = 1; off < 64; off <<= 1){
      m0 = fmaxf(m0, __shfl_xor(m0, off));
      m1 = fmaxf(m1, __shfl_xor(m1, off));
      la0 += __shfl_xor(la0, off); la1 += __shfl_xor(la1, off);
    }
    if (lane == 0){ mW[w][0]=m0; mW[w][1]=m1; laW[w][0]=la0; laW[w][1]=la1; }
    __syncthreads();
    M0 = fmaxf(mW[0][0], mW[1][0]);
    M1 = fmaxf(mW[0][1], mW[1][1]);
    sl0 = lrelu(as1[n*2+0] + ad0  + (laW[0][0]+laW[1][0])*inv);
    sl1 = lrelu(as1[n*2+1] + adv1 + (laW[0][1]+laW[1][1])*inv);
    M0 = fmaxf(M0, sl0); M1 = fmaxf(M1, sl1);
    // pass A2: one exp per edge, stored in place (own slots only)
    float s0 = 0.f, s1 = 0.f;
    for (int i = t; i < deg; i += 128){
      float e0 = expf(e0A[i] - M0);
      float e1 = expf(e1A[i] - M1);
      e0A[i] = e0; e1A[i] = e1;
      s0 += e0; s1 += e1;
    }
    for (int off = 1; off < 64; off <<= 1){
      s0 += __shfl_xor(s0, off); s1 += __shfl_xor(s1, off);
    }
    if (lane == 0){ sW[w][0]=s0; sW[w][1]=s1; }
    __syncthreads();
    es0 = expf(sl0 - M0); es1 = expf(sl1 - M1);
    S0 = sW[0][0] + sW[1][0] + es0;
    S1 = sW[0][1] + sW[1][1] + es1;
    // pass B: weighted gather
    for (int k = 0; k < deg; ++k)
      acc += eSel[k] * xh[(size_t)(srcA[k] + t)];
  } else {
    // fallback (deg > CAP1): 3-pass recompute — correctness path, ~never taken
    float m0 = -INFINITY, m1 = -INFINITY, la0 = 0.f, la1 = 0.f;
    for (int i = t; i < deg; i += 128){
      float4 r = erec[(size_t)beg + i];
      int s = __float_as_int(r.x);
      float2 a = *(const float2*)&as1[s*2];
      m0 = fmaxf(m0, lrelu(a.x + ad0  + r.y));
      m1 = fmaxf(m1, lrelu(a.y + adv1 + r.z));
      la0 += r.y; la1 += r.z;
    }
    for (int off = 1; off < 64; off <<= 1){
      m0 = fmaxf(m0, __shfl_xor(m0, off));
      m1 = fmaxf(m1, __shfl_xor(m1, off));
      la0 += __shfl_xor(la0, off); la1 += __shfl_xor(la1, off);
    }
    if (lane == 0){ mW[w][0]=m0; mW[w][1]=m1; laW[w][0]=la0; laW[w][1]=la1; }
    __syncthreads();
    M0 = fmaxf(mW[0][0], mW[1][0]);
    M1 = fmaxf(mW[0][1], mW[1][1]);
    sl0 = lrelu(as1[n*2+0] + ad0  + (laW[0][0]+laW[1][0])*inv);
    sl1 = lrelu(as1[n*2+1] + adv1 + (laW[0][1]+laW[1][1])*inv);
    M0 = fmaxf(M0, sl0); M1 = fmaxf(M1, sl1);
    float s0 = 0.f, s1 = 0.f;
    for (int i = t; i < deg; i += 128){
      float4 r = erec[(size_t)beg + i];
      int s = __float_as_int(r.x);
      float2 a = *(const float2*)&as1[s*2];
      s0 += expf(lrelu(a.x + ad0  + r.y) - M0);
      s1 += expf(lrelu(a.y + adv1 + r.z) - M1);
    }
    for (int off = 1; off < 64; off <<= 1){
      s0 += __shfl_xor(s0, off); s1 += __shfl_xor(s1, off);
    }
    if (lane == 0){ sW[w][0]=s0; sW[w][1]=s1; }
    __syncthreads();
    es0 = expf(sl0 - M0); es1 = expf(sl1 - M1);
    S0 = sW[0][0] + sW[1][0] + es0;
    S1 = sW[0][1] + sW[1][1] + es1;
    for (int base = 0; base < deg; base += CAP1){
      int c = min(CAP1, deg - base);
      __syncthreads();
      for (int i = t; i < c; i += 128){
        float4 r = erec[(size_t)beg + base + i];
        int s = __float_as_int(r.x);
        float2 a = *(const float2*)&as1[s*2];
        srcA[i] = s * C1;
        e0A[i] = expf(lrelu(a.x + ad0  + r.y) - M0);
        e1A[i] = expf(lrelu(a.y + adv1 + r.z) - M1);
      }
      __syncthreads();
      for (int k = 0; k < c; ++k)
        acc += eSel[k] * xh[(size_t)(srcA[k] + t)];
    }
  }
  acc += ((t < 64) ? es0 : es1) * xh[(size_t)n*C1 + t];
  float v = acc / (((t < 64) ? S0 : S1) + 1e-16f) + b1[t];
  h1[(size_t)n*C1 + t] = v > 0.f ? v : expm1f(v);   // ELU
}

// ---------------- K8: xh2 = h1 @ W2 ([N,128]@[128,40]) ----------------
#define G2_ROWS 6
__global__ void __launch_bounds__(256) k_gemm2(const float* __restrict__ h1,
                                               const float* __restrict__ W2,
                                               float* __restrict__ xh2){
  __shared__ float wt[F_IN*OUT_C];
  __shared__ float xt[G2_ROWS][F_IN];
  int t = threadIdx.x;
  for (int i = t; i < F_IN*OUT_C; i += 256) wt[i] = W2[i];
  int r0 = blockIdx.x * G2_ROWS;
  for (int i = t; i < G2_ROWS*F_IN; i += 256){
    int r = i >> 7, c = i & 127;
    int row = r0 + r;
    xt[r][c] = (row < N_NODES) ? h1[(size_t)row*F_IN + c] : 0.f;
  }
  __syncthreads();
  if (t < G2_ROWS*OUT_C){
    int lr = t / OUT_C, c = t % OUT_C;
    int row = r0 + lr;
    if (row < N_NODES){
      float acc = 0.f;
      for (int k = 0; k < F_IN; k += 4){
        float4 xv = *(const float4*)&xt[lr][k];
        acc += xv.x*wt[(k+0)*OUT_C + c] + xv.y*wt[(k+1)*OUT_C + c]
             + xv.z*wt[(k+2)*OUT_C + c] + xv.w*wt[(k+3)*OUT_C + c];
      }
      xh2[(size_t)row*OUT_C + c] = acc;
    }
  }
}

// ---------------- K9: per-node attention scalars layer 2 ----------------
__global__ void k_att2(const float* __restrict__ xh2, const float* __restrict__ a_src,
                       const float* __restrict__ a_dst,
                       float* __restrict__ as_o, float* __restrict__ ad_o){
  int node = blockIdx.x * (blockDim.x >> 6) + (threadIdx.x >> 6);
  int lane = threadIdx.x & 63;
  if (node >= N_NODES) return;
  float v = (lane < OUT_C) ? xh2[(size_t)node*OUT_C + lane] : 0.f;
  float s = (lane < OUT_C) ? v*a_src[lane] : 0.f;
  float d = (lane < OUT_C) ? v*a_dst[lane] : 0.f;
  for (int off = 1; off < 64; off <<= 1){
    s += __shfl_xor(s, off);
    d += __shfl_xor(d, off);
  }
  if (lane == 0){ as_o[node] = s; ad_o[node] = d; }
}

// ---------------- K10: layer-2 aggregation + log_softmax, logit-cached ----------------
__global__ void __launch_bounds__(64) k_agg2(const float* __restrict__ xh2,
    const int* __restrict__ rowptr, const float4* __restrict__ erec,
    const float* __restrict__ as2, const float* __restrict__ ad2,
    const float* __restrict__ b2, float* __restrict__ out){
  __shared__ int   srcA[CAP2];
  __shared__ float eA[CAP2];
  int n = blockIdx.x, t = threadIdx.x;
  int beg = rowptr[n], end = rowptr[n+1];
  int deg = end - beg;
  float adv = ad2[n];
  float inv = 1.f / fmaxf((float)deg, 1.f);
  float M, sl, es, S;
  float acc = 0.f;

  if (deg <= CAP2){
    float m = -INFINITY, la = 0.f;
    for (int i = t; i < deg; i += 64){
      float4 r = erec[(size_t)beg + i];
      int s = __float_as_int(r.x);
      float lg = lrelu(as2[s] + adv + r.w);
      srcA[i] = s * OUT_C;
      eA[i] = lg;
      m = fmaxf(m, lg);
      la += r.w;
    }
    for (int off = 1; off < 64; off <<= 1){
      m = fmaxf(m, __shfl_xor(m, off));
      la += __shfl_xor(la, off);
    }
    sl = lrelu(as2[n] + adv + la*inv);
    M = fmaxf(m, sl);
    float ss = 0.f;
    __syncthreads();
    for (int i = t; i < deg; i += 64){
      float e = expf(eA[i] - M);
      eA[i] = e;
      ss += e;
    }
    for (int off = 1; off < 64; off <<= 1) ss += __shfl_xor(ss, off);
    es = expf(sl - M);
    S = ss + es;
    __syncthreads();
    if (t < OUT_C)
      for (int k = 0; k < deg; ++k) acc += eA[k] * xh2[(size_t)(srcA[k] + t)];
  } else {
    // fallback, ~never taken
    float m = -INFINITY, la = 0.f;
    for (int i = t; i < deg; i += 64){
      float4 r = erec[(size_t)beg + i];
      int s = __float_as_int(r.x);
      m = fmaxf(m, lrelu(as2[s] + adv + r.w));
      la += r.w;
    }
    for (int off = 1; off < 64; off <<= 1){
      m = fmaxf(m, __shfl_xor(m, off));
      la += __shfl_xor(la, off);
    }
    sl = lrelu(as2[n] + adv + la*inv);
    M = fmaxf(m, sl);
    float ss = 0.f;
    for (int i = t; i < deg; i += 64){
      float4 r = erec[(size_t)beg + i];
      int s = __float_as_int(r.x);
      ss += expf(lrelu(as2[s] + adv + r.w) - M);
    }
    for (int off = 1; off < 64; off <<= 1) ss += __shfl_xor(ss, off);
    es = expf(sl - M);
    S = ss + es;
    for (int base = 0; base < deg; base += CAP2){
      int c = min(CAP2, deg - base);
      __syncthreads();
      for (int i = t; i < c; i += 64){
        float4 r = erec[(size_t)beg + base + i];
        int s = __float_as_int(r.x);
        srcA[i] = s * OUT_C;
        eA[i] = expf(lrelu(as2[s] + adv + r.w) - M);
      }
      __syncthreads();
      if (t < OUT_C)
        for (int k = 0; k < c; ++k) acc += eA[k] * xh2[(size_t)(srcA[k] + t)];
    }
  }
  float o;
  if (t < OUT_C){
    acc += es * xh2[(size_t)n*OUT_C + t];
    o = acc / (S + 1e-16f) + b2[t];
  } else {
    o = -INFINITY;
  }
  // log_softmax over the 40 columns
  float mm = o;
  for (int off = 1; off < 64; off <<= 1) mm = fmaxf(mm, __shfl_xor(mm, off));
  float e = (t < OUT_C) ? expf(o - mm) : 0.f;
  for (int off = 1; off < 64; off <<= 1) e += __shfl_xor(e, off);
  if (t < OUT_C) out[(size_t)n*OUT_C + t] = o - mm - logf(e);
}

// ---------------- host launcher ----------------
extern "C" void kernel_launch(void* const* d_in, const int* in_sizes, int n_in,
                              void* d_out, int out_size, void* d_ws, size_t ws_size,
                              hipStream_t stream){
  const float* x        = (const float*)d_in[0];
  const int*   ei       = (const int*)  d_in[1];
  const float* eattr    = (const float*)d_in[2];
  const float* W1       = (const float*)d_in[3];
  const float* att_src1 = (const float*)d_in[4];
  const float* att_dst1 = (const float*)d_in[5];
  const float* We1      = (const float*)d_in[6];
  const float* att_e1   = (const float*)d_in[7];
  const float* b1       = (const float*)d_in[8];
  const float* W2       = (const float*)d_in[9];
  const float* att_src2 = (const float*)d_in[10];
  const float* att_dst2 = (const float*)d_in[11];
  const float* We2      = (const float*)d_in[12];
  const float* att_e2   = (const float*)d_in[13];
  const float* b2       = (const float*)d_in[14];
  const int* src = ei;
  const int* dst = ei + N_EDGES;

  float* wsf    = (float*)d_ws;
  int*   cnt     = (int*)(wsf + O_CNT);
  int*   fill    = (int*)(wsf + O_FILL);
  int*   rowptr  = (int*)(wsf + O_ROWPTR);
  float4* erec   = (float4*)(wsf + O_EREC);
  float* weatt   = wsf + O_WEATT;
  float* xh1     = wsf + O_XH1;
  float* as1     = wsf + O_AS1;
  float* ad1     = wsf + O_AD1;
  float* h1      = wsf + O_H1;
  float* xh2     = wsf + O_XH2;
  float* as2     = wsf + O_AS2;
  float* ad2     = wsf + O_AD2;
  float* out     = (float*)d_out;

  hipMemsetAsync(wsf + O_CNT, 0, O_ZERO_END*sizeof(float), stream);

  const int EB = (N_EDGES + 255) / 256;

  k_weatt  <<<1, 64, 0, stream>>>(We1, att_e1, We2, att_e2, weatt);
  k_count  <<<EB, 256, 0, stream>>>(dst, cnt);
  k_scan   <<<1, 1024, 0, stream>>>(cnt, rowptr);
  k_scatter<<<EB, 256, 0, stream>>>(src, dst, eattr, rowptr, fill, weatt, erec);

  k_gemm1  <<<(N_NODES + G1_ROWS - 1)/G1_ROWS, 128, 0, stream>>>(x, W1, xh1);
  k_att1   <<<(N_NODES + 3)/4, 256, 0, stream>>>(xh1, att_src1, att_dst1, as1, ad1);
  k_agg1   <<<N_NODES, 128, 0, stream>>>(xh1, rowptr, erec, as1, ad1, b1, h1);

  k_gemm2  <<<(N_NODES + G2_ROWS - 1)/G2_ROWS, 256, 0, stream>>>(h1, W2, xh2);
  k_att2   <<<(N_NODES + 3)/4, 256, 0, stream>>>(xh2, att_src2, att_dst2, as2, ad2);
  k_agg2   <<<N_NODES, 64, 0, stream>>>(xh2, rowptr, erec, as2, ad2, b2, out);
}

// Round 4
// 431.486 us; speedup vs baseline: 1.5956x; 1.0773x over previous
//
#include <hip/hip_runtime.h>
#include <math.h>

#define N_NODES 50000
#define N_EDGES 800000
#define F_IN    128
#define HID     64
#define HEADS   2
#define C1      128   // HEADS*HID
#define OUT_C   40
#define EDIM    5
#define NEG_SLOPE 0.2f
#define CAP1    768   // LDS edge cache, layer-1 agg (Poisson(16) => never exceeded; fallback kept)
#define CAP2    512   // LDS edge cache, layer-2 agg

// ---------------- workspace layout (element offsets, 4B units) ----------------
constexpr size_t pad64(size_t n){ return (n + 63) / 64 * 64; }
constexpr size_t O_CNT      = 0;
constexpr size_t O_FILL     = O_CNT      + pad64(N_NODES);
constexpr size_t O_ZERO_END = O_FILL     + pad64(N_NODES);
constexpr size_t O_ROWPTR   = O_ZERO_END;
constexpr size_t O_EREC     = O_ROWPTR   + pad64(N_NODES+1);   // float4 per edge {src, l1h0, l1h1, l2}
constexpr size_t O_WEATT    = O_EREC     + pad64((size_t)N_EDGES*4);
constexpr size_t O_XH1      = O_WEATT    + 64;
constexpr size_t O_AS1      = O_XH1      + pad64((size_t)N_NODES*C1);
constexpr size_t O_AD1      = O_AS1      + pad64((size_t)N_NODES*2);
constexpr size_t O_H1       = O_AD1      + pad64((size_t)N_NODES*2);
constexpr size_t O_XH2      = O_H1       + pad64((size_t)N_NODES*C1);
constexpr size_t O_AS2      = O_XH2      + pad64((size_t)N_NODES*OUT_C);
constexpr size_t O_AD2      = O_AS2      + pad64(N_NODES);

__device__ __forceinline__ float lrelu(float v){ return v >= 0.f ? v : NEG_SLOPE*v; }

// ---------------- K0: tiny attention-projection matrices ----------------
__global__ void k_weatt(const float* __restrict__ We1, const float* __restrict__ ae1,
                        const float* __restrict__ We2, const float* __restrict__ ae2,
                        float* __restrict__ weatt){
  int t = threadIdx.x;
  if (t < 10){
    int k = t >> 1, h = t & 1;
    float s = 0.f;
    for (int c = 0; c < HID; c++) s += We1[k*C1 + h*HID + c] * ae1[h*HID + c];
    weatt[k*2 + h] = s;
  } else if (t < 15){
    int k = t - 10;
    float s = 0.f;
    for (int c = 0; c < OUT_C; c++) s += We2[k*OUT_C + c] * ae2[c];
    weatt[10 + k] = s;
  }
}

// ---------------- K1: in-degree (int atomics, L2-resident) ----------------
__global__ void k_count(const int* __restrict__ dst, int* __restrict__ cnt){
  int e = blockIdx.x*blockDim.x + threadIdx.x;
  if (e >= N_EDGES) return;
  atomicAdd(&cnt[dst[e]], 1);
}

// ---------------- K2: exclusive scan of cnt -> rowptr ----------------
__global__ void __launch_bounds__(1024) k_scan(const int* __restrict__ cnt, int* __restrict__ rowptr){
  __shared__ int part[1024];
  int t = threadIdx.x;
  const int CH = (N_NODES + 1023) / 1024;
  int base = t * CH;
  int s = 0;
  for (int i = 0; i < CH; i++){ int idx = base + i; if (idx < N_NODES) s += cnt[idx]; }
  part[t] = s; __syncthreads();
  for (int off = 1; off < 1024; off <<= 1){
    int v = (t >= off) ? part[t - off] : 0;
    __syncthreads();
    part[t] += v;
    __syncthreads();
  }
  int run = (t == 0) ? 0 : part[t - 1];
  for (int i = 0; i < CH; i++){
    int idx = base + i;
    if (idx < N_NODES){ rowptr[idx] = run; run += cnt[idx]; }
  }
  if (t == 1023) rowptr[N_NODES] = part[1023];
}

// ---------------- K3: scatter edges into CSR as interleaved float4 records ----------------
__global__ void k_scatter(const int* __restrict__ src, const int* __restrict__ dst,
                          const float* __restrict__ eattr, const int* __restrict__ rowptr,
                          int* __restrict__ fill, const float* __restrict__ weatt,
                          float4* __restrict__ erec){
  int e = blockIdx.x*blockDim.x + threadIdx.x;
  if (e >= N_EDGES) return;
  int d = dst[e];
  int pos = rowptr[d] + atomicAdd(&fill[d], 1);
  float a[EDIM];
  #pragma unroll
  for (int k = 0; k < EDIM; k++) a[k] = eattr[e*EDIM + k];
  float l0 = 0.f, l1 = 0.f, l2 = 0.f;
  #pragma unroll
  for (int k = 0; k < EDIM; k++){
    l0 += a[k]*weatt[k*2 + 0];
    l1 += a[k]*weatt[k*2 + 1];
    l2 += a[k]*weatt[10 + k];
  }
  erec[pos] = make_float4(__int_as_float(src[e]), l0, l1, l2);
}

// ---------------- K5: xh1 = x @ W1  ([N,128]@[128,128]) ----------------
#define G1_ROWS 32
__global__ void __launch_bounds__(128) k_gemm1(const float* __restrict__ x,
                                               const float* __restrict__ W,
                                               float* __restrict__ xh){
  __shared__ float xt[G1_ROWS][F_IN];
  int t = threadIdx.x;
  int r0 = blockIdx.x * G1_ROWS;
  for (int r = 0; r < G1_ROWS; r++){
    int row = r0 + r;
    xt[r][t] = (row < N_NODES) ? x[(size_t)row*F_IN + t] : 0.f;
  }
  __syncthreads();
  float acc[G1_ROWS];
  #pragma unroll
  for (int r = 0; r < G1_ROWS; r++) acc[r] = 0.f;
  for (int k = 0; k < F_IN; k += 4){
    float w0 = W[(k+0)*C1 + t], w1 = W[(k+1)*C1 + t];
    float w2 = W[(k+2)*C1 + t], w3 = W[(k+3)*C1 + t];
    #pragma unroll
    for (int r = 0; r < G1_ROWS; r++){
      float4 xv = *(const float4*)&xt[r][k];
      acc[r] += xv.x*w0 + xv.y*w1 + xv.z*w2 + xv.w*w3;
    }
  }
  for (int r = 0; r < G1_ROWS; r++){
    int row = r0 + r;
    if (row < N_NODES) xh[(size_t)row*C1 + t] = acc[r];
  }
}

// ---------------- K6: per-node attention scalars layer 1 (wave per node) ----------------
__global__ void k_att1(const float* __restrict__ xh, const float* __restrict__ a_src,
                       const float* __restrict__ a_dst,
                       float* __restrict__ as_o, float* __restrict__ ad_o){
  int node = blockIdx.x * (blockDim.x >> 6) + (threadIdx.x >> 6);
  int lane = threadIdx.x & 63;
  if (node >= N_NODES) return;
  float x0 = xh[(size_t)node*C1 + lane];
  float x1 = xh[(size_t)node*C1 + 64 + lane];
  float s0 = x0*a_src[lane],     s1 = x1*a_src[64 + lane];
  float d0 = x0*a_dst[lane],     d1 = x1*a_dst[64 + lane];
  for (int off = 1; off < 64; off <<= 1){
    s0 += __shfl_xor(s0, off); s1 += __shfl_xor(s1, off);
    d0 += __shfl_xor(d0, off); d1 += __shfl_xor(d1, off);
  }
  if (lane == 0){
    as_o[node*2+0] = s0; as_o[node*2+1] = s1;
    ad_o[node*2+0] = d0; ad_o[node*2+1] = d1;
  }
}

// ---------------- K7: layer-1 aggregation; phase-B = 4 edges in flight, float4 lanes ----------------
__global__ void __launch_bounds__(128) k_agg1(const float* __restrict__ xh,
    const int* __restrict__ rowptr, const float4* __restrict__ erec,
    const float* __restrict__ as1, const float* __restrict__ ad1,
    const float* __restrict__ b1, float* __restrict__ h1){
  __shared__ int   srcA[CAP1];
  __shared__ float e0A[CAP1], e1A[CAP1];
  __shared__ float mW[2][2], laW[2][2], sW[2][2];
  __shared__ float4 redL[32];
  int n = blockIdx.x, t = threadIdx.x;
  int w = t >> 6, lane = t & 63;
  int beg = rowptr[n], end = rowptr[n+1];
  int deg = end - beg;
  float ad0 = ad1[n*2+0], adv1 = ad1[n*2+1];
  float inv = 1.f / fmaxf((float)deg, 1.f);
  float M0, M1, sl0, sl1, es0, es1, S0, S1;

  if (deg <= CAP1){
    // pass A: logits -> LDS, plain max + ale-sum reduce
    float m0 = -INFINITY, m1 = -INFINITY, la0 = 0.f, la1 = 0.f;
    for (int i = t; i < deg; i += 128){
      float4 r = erec[(size_t)beg + i];
      int s = __float_as_int(r.x);
      float2 a = *(const float2*)&as1[s*2];
      float lg0 = lrelu(a.x + ad0  + r.y);
      float lg1 = lrelu(a.y + adv1 + r.z);
      srcA[i] = s * C1;
      e0A[i] = lg0; e1A[i] = lg1;
      m0 = fmaxf(m0, lg0); m1 = fmaxf(m1, lg1);
      la0 += r.y; la1 += r.z;
    }
    for (int off = 1; off < 64; off <<= 1){
      m0 = fmaxf(m0, __shfl_xor(m0, off));
      m1 = fmaxf(m1, __shfl_xor(m1, off));
      la0 += __shfl_xor(la0, off); la1 += __shfl_xor(la1, off);
    }
    if (lane == 0){ mW[w][0]=m0; mW[w][1]=m1; laW[w][0]=la0; laW[w][1]=la1; }
    __syncthreads();
    M0 = fmaxf(mW[0][0], mW[1][0]);
    M1 = fmaxf(mW[0][1], mW[1][1]);
    sl0 = lrelu(as1[n*2+0] + ad0  + (laW[0][0]+laW[1][0])*inv);
    sl1 = lrelu(as1[n*2+1] + adv1 + (laW[0][1]+laW[1][1])*inv);
    M0 = fmaxf(M0, sl0); M1 = fmaxf(M1, sl1);
    // pass A2: one exp per edge, stored in place (own slots only)
    float s0 = 0.f, s1 = 0.f;
    for (int i = t; i < deg; i += 128){
      float e0 = expf(e0A[i] - M0);
      float e1 = expf(e1A[i] - M1);
      e0A[i] = e0; e1A[i] = e1;
      s0 += e0; s1 += e1;
    }
    for (int off = 1; off < 64; off <<= 1){
      s0 += __shfl_xor(s0, off); s1 += __shfl_xor(s1, off);
    }
    if (lane == 0){ sW[w][0]=s0; sW[w][1]=s1; }
    __syncthreads();
    es0 = expf(sl0 - M0); es1 = expf(sl1 - M1);
    S0 = sW[0][0] + sW[1][0] + es0;
    S1 = sW[0][1] + sW[1][1] + es1;
    // phase B: 4 edge-groups x 32 lanes; each lane = float4 of one source row
    int q = t >> 5, lane32 = t & 31;
    bool head0 = (lane32 < 16);
    float4 acc = make_float4(0.f, 0.f, 0.f, 0.f);
    for (int k0 = 0; k0 < deg; k0 += 4){
      int k = k0 + q;
      if (k < deg){
        float e = head0 ? e0A[k] : e1A[k];
        float4 r = ((const float4*)&xh[srcA[k]])[lane32];
        acc.x += e*r.x; acc.y += e*r.y; acc.z += e*r.z; acc.w += e*r.w;
      }
    }
    // combine group pairs within each wave (q0+q1 in wave0, q2+q3 in wave1)
    acc.x += __shfl_xor(acc.x, 32);
    acc.y += __shfl_xor(acc.y, 32);
    acc.z += __shfl_xor(acc.z, 32);
    acc.w += __shfl_xor(acc.w, 32);
    if (t >= 64 && t < 96) redL[t - 64] = acc;
    __syncthreads();
    if (t < 32){
      float4 r2 = redL[t];
      acc.x += r2.x; acc.y += r2.y; acc.z += r2.z; acc.w += r2.w;
      // self-loop + bias + ELU + store (cols t*4..t*4+3; head0 iff t<16)
      float es = head0 ? es0 : es1;
      float den = (head0 ? S0 : S1) + 1e-16f;
      float4 xs = ((const float4*)&xh[(size_t)n*C1])[t];
      float4 bv = ((const float4*)b1)[t];
      float4 o;
      o.x = (acc.x + es*xs.x)/den + bv.x;
      o.y = (acc.y + es*xs.y)/den + bv.y;
      o.z = (acc.z + es*xs.z)/den + bv.z;
      o.w = (acc.w + es*xs.w)/den + bv.w;
      o.x = o.x > 0.f ? o.x : expm1f(o.x);
      o.y = o.y > 0.f ? o.y : expm1f(o.y);
      o.z = o.z > 0.f ? o.z : expm1f(o.z);
      o.w = o.w > 0.f ? o.w : expm1f(o.w);
      ((float4*)&h1[(size_t)n*C1])[t] = o;
    }
    return;
  }

  // fallback (deg > CAP1): 3-pass recompute, column-per-thread — correctness path, ~never taken
  {
    float m0 = -INFINITY, m1 = -INFINITY, la0 = 0.f, la1 = 0.f;
    for (int i = t; i < deg; i += 128){
      float4 r = erec[(size_t)beg + i];
      int s = __float_as_int(r.x);
      float2 a = *(const float2*)&as1[s*2];
      m0 = fmaxf(m0, lrelu(a.x + ad0  + r.y));
      m1 = fmaxf(m1, lrelu(a.y + adv1 + r.z));
      la0 += r.y; la1 += r.z;
    }
    for (int off = 1; off < 64; off <<= 1){
      m0 = fmaxf(m0, __shfl_xor(m0, off));
      m1 = fmaxf(m1, __shfl_xor(m1, off));
      la0 += __shfl_xor(la0, off); la1 += __shfl_xor(la1, off);
    }
    if (lane == 0){ mW[w][0]=m0; mW[w][1]=m1; laW[w][0]=la0; laW[w][1]=la1; }
    __syncthreads();
    M0 = fmaxf(mW[0][0], mW[1][0]);
    M1 = fmaxf(mW[0][1], mW[1][1]);
    sl0 = lrelu(as1[n*2+0] + ad0  + (laW[0][0]+laW[1][0])*inv);
    sl1 = lrelu(as1[n*2+1] + adv1 + (laW[0][1]+laW[1][1])*inv);
    M0 = fmaxf(M0, sl0); M1 = fmaxf(M1, sl1);
    float s0 = 0.f, s1 = 0.f;
    for (int i = t; i < deg; i += 128){
      float4 r = erec[(size_t)beg + i];
      int s = __float_as_int(r.x);
      float2 a = *(const float2*)&as1[s*2];
      s0 += expf(lrelu(a.x + ad0  + r.y) - M0);
      s1 += expf(lrelu(a.y + adv1 + r.z) - M1);
    }
    for (int off = 1; off < 64; off <<= 1){
      s0 += __shfl_xor(s0, off); s1 += __shfl_xor(s1, off);
    }
    if (lane == 0){ sW[w][0]=s0; sW[w][1]=s1; }
    __syncthreads();
    es0 = expf(sl0 - M0); es1 = expf(sl1 - M1);
    S0 = sW[0][0] + sW[1][0] + es0;
    S1 = sW[0][1] + sW[1][1] + es1;
    const float* eSel = (t < 64) ? e0A : e1A;
    float acc = 0.f;
    for (int base = 0; base < deg; base += CAP1){
      int c = min(CAP1, deg - base);
      __syncthreads();
      for (int i = t; i < c; i += 128){
        float4 r = erec[(size_t)beg + base + i];
        int s = __float_as_int(r.x);
        float2 a = *(const float2*)&as1[s*2];
        srcA[i] = s * C1;
        e0A[i] = expf(lrelu(a.x + ad0  + r.y) - M0);
        e1A[i] = expf(lrelu(a.y + adv1 + r.z) - M1);
      }
      __syncthreads();
      for (int k = 0; k < c; ++k)
        acc += eSel[k] * xh[(size_t)(srcA[k] + t)];
    }
    acc += ((t < 64) ? es0 : es1) * xh[(size_t)n*C1 + t];
    float v = acc / (((t < 64) ? S0 : S1) + 1e-16f) + b1[t];
    h1[(size_t)n*C1 + t] = v > 0.f ? v : expm1f(v);   // ELU
  }
}

// ---------------- K8: xh2 = h1 @ W2 ([N,128]@[128,40]) ----------------
#define G2_ROWS 6
__global__ void __launch_bounds__(256) k_gemm2(const float* __restrict__ h1,
                                               const float* __restrict__ W2,
                                               float* __restrict__ xh2){
  __shared__ float wt[F_IN*OUT_C];
  __shared__ float xt[G2_ROWS][F_IN];
  int t = threadIdx.x;
  for (int i = t; i < F_IN*OUT_C; i += 256) wt[i] = W2[i];
  int r0 = blockIdx.x * G2_ROWS;
  for (int i = t; i < G2_ROWS*F_IN; i += 256){
    int r = i >> 7, c = i & 127;
    int row = r0 + r;
    xt[r][c] = (row < N_NODES) ? h1[(size_t)row*F_IN + c] : 0.f;
  }
  __syncthreads();
  if (t < G2_ROWS*OUT_C){
    int lr = t / OUT_C, c = t % OUT_C;
    int row = r0 + lr;
    if (row < N_NODES){
      float acc = 0.f;
      for (int k = 0; k < F_IN; k += 4){
        float4 xv = *(const float4*)&xt[lr][k];
        acc += xv.x*wt[(k+0)*OUT_C + c] + xv.y*wt[(k+1)*OUT_C + c]
             + xv.z*wt[(k+2)*OUT_C + c] + xv.w*wt[(k+3)*OUT_C + c];
      }
      xh2[(size_t)row*OUT_C + c] = acc;
    }
  }
}

// ---------------- K9: per-node attention scalars layer 2 ----------------
__global__ void k_att2(const float* __restrict__ xh2, const float* __restrict__ a_src,
                       const float* __restrict__ a_dst,
                       float* __restrict__ as_o, float* __restrict__ ad_o){
  int node = blockIdx.x * (blockDim.x >> 6) + (threadIdx.x >> 6);
  int lane = threadIdx.x & 63;
  if (node >= N_NODES) return;
  float v = (lane < OUT_C) ? xh2[(size_t)node*OUT_C + lane] : 0.f;
  float s = (lane < OUT_C) ? v*a_src[lane] : 0.f;
  float d = (lane < OUT_C) ? v*a_dst[lane] : 0.f;
  for (int off = 1; off < 64; off <<= 1){
    s += __shfl_xor(s, off);
    d += __shfl_xor(d, off);
  }
  if (lane == 0){ as_o[node] = s; ad_o[node] = d; }
}

// ---------------- K10: layer-2 aggregation + log_softmax, 4-way ILP gather ----------------
__global__ void __launch_bounds__(64) k_agg2(const float* __restrict__ xh2,
    const int* __restrict__ rowptr, const float4* __restrict__ erec,
    const float* __restrict__ as2, const float* __restrict__ ad2,
    const float* __restrict__ b2, float* __restrict__ out){
  __shared__ int   srcA[CAP2];
  __shared__ float eA[CAP2];
  int n = blockIdx.x, t = threadIdx.x;
  int beg = rowptr[n], end = rowptr[n+1];
  int deg = end - beg;
  float adv = ad2[n];
  float inv = 1.f / fmaxf((float)deg, 1.f);
  float M, sl, es, S;
  float acc = 0.f;

  if (deg <= CAP2){
    float m = -INFINITY, la = 0.f;
    for (int i = t; i < deg; i += 64){
      float4 r = erec[(size_t)beg + i];
      int s = __float_as_int(r.x);
      float lg = lrelu(as2[s] + adv + r.w);
      srcA[i] = s * OUT_C;
      eA[i] = lg;
      m = fmaxf(m, lg);
      la += r.w;
    }
    for (int off = 1; off < 64; off <<= 1){
      m = fmaxf(m, __shfl_xor(m, off));
      la += __shfl_xor(la, off);
    }
    sl = lrelu(as2[n] + adv + la*inv);
    M = fmaxf(m, sl);
    float ss = 0.f;
    __syncthreads();
    for (int i = t; i < deg; i += 64){
      float e = expf(eA[i] - M);
      eA[i] = e;
      ss += e;
    }
    for (int off = 1; off < 64; off <<= 1) ss += __shfl_xor(ss, off);
    es = expf(sl - M);
    S = ss + es;
    __syncthreads();
    if (t < OUT_C){
      float a0 = 0.f, a1 = 0.f, a2 = 0.f, a3 = 0.f;
      int k = 0;
      for (; k + 4 <= deg; k += 4){
        a0 += eA[k+0] * xh2[(size_t)(srcA[k+0] + t)];
        a1 += eA[k+1] * xh2[(size_t)(srcA[k+1] + t)];
        a2 += eA[k+2] * xh2[(size_t)(srcA[k+2] + t)];
        a3 += eA[k+3] * xh2[(size_t)(srcA[k+3] + t)];
      }
      for (; k < deg; ++k) a0 += eA[k] * xh2[(size_t)(srcA[k] + t)];
      acc = (a0 + a1) + (a2 + a3);
    }
  } else {
    // fallback, ~never taken
    float m = -INFINITY, la = 0.f;
    for (int i = t; i < deg; i += 64){
      float4 r = erec[(size_t)beg + i];
      int s = __float_as_int(r.x);
      m = fmaxf(m, lrelu(as2[s] + adv + r.w));
      la += r.w;
    }
    for (int off = 1; off < 64; off <<= 1){
      m = fmaxf(m, __shfl_xor(m, off));
      la += __shfl_xor(la, off);
    }
    sl = lrelu(as2[n] + adv + la*inv);
    M = fmaxf(m, sl);
    float ss = 0.f;
    for (int i = t; i < deg; i += 64){
      float4 r = erec[(size_t)beg + i];
      int s = __float_as_int(r.x);
      ss += expf(lrelu(as2[s] + adv + r.w) - M);
    }
    for (int off = 1; off < 64; off <<= 1) ss += __shfl_xor(ss, off);
    es = expf(sl - M);
    S = ss + es;
    for (int base = 0; base < deg; base += CAP2){
      int c = min(CAP2, deg - base);
      __syncthreads();
      for (int i = t; i < c; i += 64){
        float4 r = erec[(size_t)beg + base + i];
        int s = __float_as_int(r.x);
        srcA[i] = s * OUT_C;
        eA[i] = expf(lrelu(as2[s] + adv + r.w) - M);
      }
      __syncthreads();
      if (t < OUT_C)
        for (int k = 0; k < c; ++k) acc += eA[k] * xh2[(size_t)(srcA[k] + t)];
    }
  }
  float o;
  if (t < OUT_C){
    acc += es * xh2[(size_t)n*OUT_C + t];
    o = acc / (S + 1e-16f) + b2[t];
  } else {
    o = -INFINITY;
  }
  // log_softmax over the 40 columns
  float mm = o;
  for (int off = 1; off < 64; off <<= 1) mm = fmaxf(mm, __shfl_xor(mm, off));
  float e = (t < OUT_C) ? expf(o - mm) : 0.f;
  for (int off = 1; off < 64; off <<= 1) e += __shfl_xor(e, off);
  if (t < OUT_C) out[(size_t)n*OUT_C + t] = o - mm - logf(e);
}

// ---------------- host launcher ----------------
extern "C" void kernel_launch(void* const* d_in, const int* in_sizes, int n_in,
                              void* d_out, int out_size, void* d_ws, size_t ws_size,
                              hipStream_t stream){
  const float* x        = (const float*)d_in[0];
  const int*   ei       = (const int*)  d_in[1];
  const float* eattr    = (const float*)d_in[2];
  const float* W1       = (const float*)d_in[3];
  const float* att_src1 = (const float*)d_in[4];
  const float* att_dst1 = (const float*)d_in[5];
  const float* We1      = (const float*)d_in[6];
  const float* att_e1   = (const float*)d_in[7];
  const float* b1       = (const float*)d_in[8];
  const float* W2       = (const float*)d_in[9];
  const float* att_src2 = (const float*)d_in[10];
  const float* att_dst2 = (const float*)d_in[11];
  const float* We2      = (const float*)d_in[12];
  const float* att_e2   = (const float*)d_in[13];
  const float* b2       = (const float*)d_in[14];
  const int* src = ei;
  const int* dst = ei + N_EDGES;

  float* wsf    = (float*)d_ws;
  int*   cnt     = (int*)(wsf + O_CNT);
  int*   fill    = (int*)(wsf + O_FILL);
  int*   rowptr  = (int*)(wsf + O_ROWPTR);
  float4* erec   = (float4*)(wsf + O_EREC);
  float* weatt   = wsf + O_WEATT;
  float* xh1     = wsf + O_XH1;
  float* as1     = wsf + O_AS1;
  float* ad1     = wsf + O_AD1;
  float* h1      = wsf + O_H1;
  float* xh2     = wsf + O_XH2;
  float* as2     = wsf + O_AS2;
  float* ad2     = wsf + O_AD2;
  float* out     = (float*)d_out;

  hipMemsetAsync(wsf + O_CNT, 0, O_ZERO_END*sizeof(float), stream);

  const int EB = (N_EDGES + 255) / 256;

  k_weatt  <<<1, 64, 0, stream>>>(We1, att_e1, We2, att_e2, weatt);
  k_count  <<<EB, 256, 0, stream>>>(dst, cnt);
  k_scan   <<<1, 1024, 0, stream>>>(cnt, rowptr);
  k_scatter<<<EB, 256, 0, stream>>>(src, dst, eattr, rowptr, fill, weatt, erec);

  k_gemm1  <<<(N_NODES + G1_ROWS - 1)/G1_ROWS, 128, 0, stream>>>(x, W1, xh1);
  k_att1   <<<(N_NODES + 3)/4, 256, 0, stream>>>(xh1, att_src1, att_dst1, as1, ad1);
  k_agg1   <<<N_NODES, 128, 0, stream>>>(xh1, rowptr, erec, as1, ad1, b1, h1);

  k_gemm2  <<<(N_NODES + G2_ROWS - 1)/G2_ROWS, 256, 0, stream>>>(h1, W2, xh2);
  k_att2   <<<(N_NODES + 3)/4, 256, 0, stream>>>(xh2, att_src2, att_dst2, as2, ad2);
  k_agg2   <<<N_NODES, 64, 0, stream>>>(xh2, rowptr, erec, as2, ad2, b2, out);
}

// Round 5
// 345.676 us; speedup vs baseline: 1.9917x; 1.2482x over previous
//
#include <hip/hip_runtime.h>
#include <math.h>

#define N_NODES 50000
#define N_EDGES 800000
#define F_IN    128
#define HID     64
#define HEADS   2
#define C1      128   // HEADS*HID
#define OUT_C   40
#define EDIM    5
#define NEG_SLOPE 0.2f
#define CAP1    768   // LDS edge cache, layer-1 agg (Poisson(16) => never exceeded; fallback kept)
#define CAP2    512   // LDS edge cache, layer-2 agg
#define SCAN_B  256
#define SCAN_NB ((N_NODES + SCAN_B - 1) / SCAN_B)   // 196

// ---------------- workspace layout (element offsets, 4B units) ----------------
constexpr size_t pad64(size_t n){ return (n + 63) / 64 * 64; }
constexpr size_t O_CNT      = 0;
constexpr size_t O_FILL     = O_CNT      + pad64(N_NODES);
constexpr size_t O_ZERO_END = O_FILL     + pad64(N_NODES);
constexpr size_t O_ROWPTR   = O_ZERO_END;
constexpr size_t O_STMP     = O_ROWPTR   + pad64(N_NODES+1);
constexpr size_t O_BSUM     = O_STMP     + pad64(N_NODES);
constexpr size_t O_BOFF     = O_BSUM     + pad64(SCAN_NB);
constexpr size_t O_EREC     = O_BOFF     + pad64(SCAN_NB);    // float4 per edge {src, l1h0, l1h1, l2}
constexpr size_t O_WEATT    = O_EREC     + pad64((size_t)N_EDGES*4);
constexpr size_t O_XH1      = O_WEATT    + 64;
constexpr size_t O_AS1      = O_XH1      + pad64((size_t)N_NODES*C1);
constexpr size_t O_AD1      = O_AS1      + pad64((size_t)N_NODES*2);
constexpr size_t O_H1       = O_AD1      + pad64((size_t)N_NODES*2);
constexpr size_t O_XH2      = O_H1       + pad64((size_t)N_NODES*C1);
constexpr size_t O_AS2      = O_XH2      + pad64((size_t)N_NODES*OUT_C);
constexpr size_t O_AD2      = O_AS2      + pad64(N_NODES);

__device__ __forceinline__ float lrelu(float v){ return v >= 0.f ? v : NEG_SLOPE*v; }

// ---------------- K0: tiny attention-projection matrices ----------------
__global__ void k_weatt(const float* __restrict__ We1, const float* __restrict__ ae1,
                        const float* __restrict__ We2, const float* __restrict__ ae2,
                        float* __restrict__ weatt){
  int t = threadIdx.x;
  if (t < 10){
    int k = t >> 1, h = t & 1;
    float s = 0.f;
    for (int c = 0; c < HID; c++) s += We1[k*C1 + h*HID + c] * ae1[h*HID + c];
    weatt[k*2 + h] = s;
  } else if (t < 15){
    int k = t - 10;
    float s = 0.f;
    for (int c = 0; c < OUT_C; c++) s += We2[k*OUT_C + c] * ae2[c];
    weatt[10 + k] = s;
  }
}

// ---------------- K1: in-degree (int atomics, L2-resident) ----------------
__global__ void k_count(const int* __restrict__ dst, int* __restrict__ cnt){
  int e = blockIdx.x*blockDim.x + threadIdx.x;
  if (e >= N_EDGES) return;
  atomicAdd(&cnt[dst[e]], 1);
}

// ---------------- K2: device-wide exclusive scan, 3 wide dispatches ----------------
// A: per-block inclusive scan of cnt -> stmp; block totals -> bsum
__global__ void __launch_bounds__(SCAN_B) k_scan1(const int* __restrict__ cnt,
                                                  int* __restrict__ stmp,
                                                  int* __restrict__ bsum){
  int blk = blockIdx.x, t = threadIdx.x;
  int i = blk*SCAN_B + t;
  int v = (i < N_NODES) ? cnt[i] : 0;
  int lane = t & 63, w = t >> 6;
  int x = v;
  #pragma unroll
  for (int off = 1; off < 64; off <<= 1){
    int y = __shfl_up(x, off);
    if (lane >= off) x += y;
  }
  __shared__ int wsum[SCAN_B/64];
  if (lane == 63) wsum[w] = x;
  __syncthreads();
  int add = 0;
  for (int k = 0; k < w; k++) add += wsum[k];
  x += add;
  if (i < N_NODES) stmp[i] = x;
  if (t == SCAN_B-1) bsum[blk] = x;
}

// B: exclusive scan of bsum[SCAN_NB] -> boff (one block, 256 threads)
__global__ void __launch_bounds__(SCAN_B) k_scan2(const int* __restrict__ bsum,
                                                  int* __restrict__ boff){
  int t = threadIdx.x;
  int v = (t < SCAN_NB) ? bsum[t] : 0;
  int lane = t & 63, w = t >> 6;
  int x = v;
  #pragma unroll
  for (int off = 1; off < 64; off <<= 1){
    int y = __shfl_up(x, off);
    if (lane >= off) x += y;
  }
  __shared__ int wsum[SCAN_B/64];
  if (lane == 63) wsum[w] = x;
  __syncthreads();
  int add = 0;
  for (int k = 0; k < w; k++) add += wsum[k];
  x += add;                      // inclusive
  if (t < SCAN_NB) boff[t] = x - v;  // exclusive
}

// C: rowptr[i+1] = stmp[i] + boff[blk]; rowptr[0] = 0
__global__ void __launch_bounds__(SCAN_B) k_scan3(const int* __restrict__ stmp,
                                                  const int* __restrict__ boff,
                                                  int* __restrict__ rowptr){
  int blk = blockIdx.x, t = threadIdx.x;
  int i = blk*SCAN_B + t;
  if (i < N_NODES) rowptr[i+1] = stmp[i] + boff[blk];
  if (i == 0) rowptr[0] = 0;
}

// ---------------- K3: scatter edges into CSR as interleaved float4 records ----------------
__global__ void k_scatter(const int* __restrict__ src, const int* __restrict__ dst,
                          const float* __restrict__ eattr, const int* __restrict__ rowptr,
                          int* __restrict__ fill, const float* __restrict__ weatt,
                          float4* __restrict__ erec){
  int e = blockIdx.x*blockDim.x + threadIdx.x;
  if (e >= N_EDGES) return;
  int d = dst[e];
  int pos = rowptr[d] + atomicAdd(&fill[d], 1);
  float a[EDIM];
  #pragma unroll
  for (int k = 0; k < EDIM; k++) a[k] = eattr[e*EDIM + k];
  float l0 = 0.f, l1 = 0.f, l2 = 0.f;
  #pragma unroll
  for (int k = 0; k < EDIM; k++){
    l0 += a[k]*weatt[k*2 + 0];
    l1 += a[k]*weatt[k*2 + 1];
    l2 += a[k]*weatt[10 + k];
  }
  erec[pos] = make_float4(__int_as_float(src[e]), l0, l1, l2);
}

// ---------------- K5: xh1 = x @ W1  ([N,128]@[128,128]) ----------------
#define G1_ROWS 32
__global__ void __launch_bounds__(128) k_gemm1(const float* __restrict__ x,
                                               const float* __restrict__ W,
                                               float* __restrict__ xh){
  __shared__ float xt[G1_ROWS][F_IN];
  int t = threadIdx.x;
  int r0 = blockIdx.x * G1_ROWS;
  for (int r = 0; r < G1_ROWS; r++){
    int row = r0 + r;
    xt[r][t] = (row < N_NODES) ? x[(size_t)row*F_IN + t] : 0.f;
  }
  __syncthreads();
  float acc[G1_ROWS];
  #pragma unroll
  for (int r = 0; r < G1_ROWS; r++) acc[r] = 0.f;
  for (int k = 0; k < F_IN; k += 4){
    float w0 = W[(k+0)*C1 + t], w1 = W[(k+1)*C1 + t];
    float w2 = W[(k+2)*C1 + t], w3 = W[(k+3)*C1 + t];
    #pragma unroll
    for (int r = 0; r < G1_ROWS; r++){
      float4 xv = *(const float4*)&xt[r][k];
      acc[r] += xv.x*w0 + xv.y*w1 + xv.z*w2 + xv.w*w3;
    }
  }
  for (int r = 0; r < G1_ROWS; r++){
    int row = r0 + r;
    if (row < N_NODES) xh[(size_t)row*C1 + t] = acc[r];
  }
}

// ---------------- K6: per-node attention scalars layer 1 (wave per node) ----------------
__global__ void k_att1(const float* __restrict__ xh, const float* __restrict__ a_src,
                       const float* __restrict__ a_dst,
                       float* __restrict__ as_o, float* __restrict__ ad_o){
  int node = blockIdx.x * (blockDim.x >> 6) + (threadIdx.x >> 6);
  int lane = threadIdx.x & 63;
  if (node >= N_NODES) return;
  float x0 = xh[(size_t)node*C1 + lane];
  float x1 = xh[(size_t)node*C1 + 64 + lane];
  float s0 = x0*a_src[lane],     s1 = x1*a_src[64 + lane];
  float d0 = x0*a_dst[lane],     d1 = x1*a_dst[64 + lane];
  for (int off = 1; off < 64; off <<= 1){
    s0 += __shfl_xor(s0, off); s1 += __shfl_xor(s1, off);
    d0 += __shfl_xor(d0, off); d1 += __shfl_xor(d1, off);
  }
  if (lane == 0){
    as_o[node*2+0] = s0; as_o[node*2+1] = s1;
    ad_o[node*2+0] = d0; ad_o[node*2+1] = d1;
  }
}

// ---------------- K7: layer-1 aggregation; phase-B = 4 edges in flight, float4 lanes ----------------
__global__ void __launch_bounds__(128) k_agg1(const float* __restrict__ xh,
    const int* __restrict__ rowptr, const float4* __restrict__ erec,
    const float* __restrict__ as1, const float* __restrict__ ad1,
    const float* __restrict__ b1, float* __restrict__ h1){
  __shared__ int   srcA[CAP1];
  __shared__ float e0A[CAP1], e1A[CAP1];
  __shared__ float mW[2][2], laW[2][2], sW[2][2];
  __shared__ float4 redL[32];
  int n = blockIdx.x, t = threadIdx.x;
  int w = t >> 6, lane = t & 63;
  int beg = rowptr[n], end = rowptr[n+1];
  int deg = end - beg;
  float ad0 = ad1[n*2+0], adv1 = ad1[n*2+1];
  float inv = 1.f / fmaxf((float)deg, 1.f);
  float M0, M1, sl0, sl1, es0, es1, S0, S1;

  if (deg <= CAP1){
    // pass A: logits -> LDS, plain max + ale-sum reduce
    float m0 = -INFINITY, m1 = -INFINITY, la0 = 0.f, la1 = 0.f;
    for (int i = t; i < deg; i += 128){
      float4 r = erec[(size_t)beg + i];
      int s = __float_as_int(r.x);
      float2 a = *(const float2*)&as1[s*2];
      float lg0 = lrelu(a.x + ad0  + r.y);
      float lg1 = lrelu(a.y + adv1 + r.z);
      srcA[i] = s * C1;
      e0A[i] = lg0; e1A[i] = lg1;
      m0 = fmaxf(m0, lg0); m1 = fmaxf(m1, lg1);
      la0 += r.y; la1 += r.z;
    }
    for (int off = 1; off < 64; off <<= 1){
      m0 = fmaxf(m0, __shfl_xor(m0, off));
      m1 = fmaxf(m1, __shfl_xor(m1, off));
      la0 += __shfl_xor(la0, off); la1 += __shfl_xor(la1, off);
    }
    if (lane == 0){ mW[w][0]=m0; mW[w][1]=m1; laW[w][0]=la0; laW[w][1]=la1; }
    __syncthreads();
    M0 = fmaxf(mW[0][0], mW[1][0]);
    M1 = fmaxf(mW[0][1], mW[1][1]);
    sl0 = lrelu(as1[n*2+0] + ad0  + (laW[0][0]+laW[1][0])*inv);
    sl1 = lrelu(as1[n*2+1] + adv1 + (laW[0][1]+laW[1][1])*inv);
    M0 = fmaxf(M0, sl0); M1 = fmaxf(M1, sl1);
    // pass A2: one exp per edge, stored in place (own slots only)
    float s0 = 0.f, s1 = 0.f;
    for (int i = t; i < deg; i += 128){
      float e0 = expf(e0A[i] - M0);
      float e1 = expf(e1A[i] - M1);
      e0A[i] = e0; e1A[i] = e1;
      s0 += e0; s1 += e1;
    }
    for (int off = 1; off < 64; off <<= 1){
      s0 += __shfl_xor(s0, off); s1 += __shfl_xor(s1, off);
    }
    if (lane == 0){ sW[w][0]=s0; sW[w][1]=s1; }
    __syncthreads();
    es0 = expf(sl0 - M0); es1 = expf(sl1 - M1);
    S0 = sW[0][0] + sW[1][0] + es0;
    S1 = sW[0][1] + sW[1][1] + es1;
    // phase B: 4 edge-groups x 32 lanes; each lane = float4 of one source row
    int q = t >> 5, lane32 = t & 31;
    bool head0 = (lane32 < 16);
    float4 acc = make_float4(0.f, 0.f, 0.f, 0.f);
    for (int k0 = 0; k0 < deg; k0 += 4){
      int k = k0 + q;
      if (k < deg){
        float e = head0 ? e0A[k] : e1A[k];
        float4 r = ((const float4*)&xh[srcA[k]])[lane32];
        acc.x += e*r.x; acc.y += e*r.y; acc.z += e*r.z; acc.w += e*r.w;
      }
    }
    // combine group pairs within each wave (q0+q1 in wave0, q2+q3 in wave1)
    acc.x += __shfl_xor(acc.x, 32);
    acc.y += __shfl_xor(acc.y, 32);
    acc.z += __shfl_xor(acc.z, 32);
    acc.w += __shfl_xor(acc.w, 32);
    if (t >= 64 && t < 96) redL[t - 64] = acc;
    __syncthreads();
    if (t < 32){
      float4 r2 = redL[t];
      acc.x += r2.x; acc.y += r2.y; acc.z += r2.z; acc.w += r2.w;
      // self-loop + bias + ELU + store (cols t*4..t*4+3; head0 iff t<16)
      float es = head0 ? es0 : es1;
      float den = (head0 ? S0 : S1) + 1e-16f;
      float4 xs = ((const float4*)&xh[(size_t)n*C1])[t];
      float4 bv = ((const float4*)b1)[t];
      float4 o;
      o.x = (acc.x + es*xs.x)/den + bv.x;
      o.y = (acc.y + es*xs.y)/den + bv.y;
      o.z = (acc.z + es*xs.z)/den + bv.z;
      o.w = (acc.w + es*xs.w)/den + bv.w;
      o.x = o.x > 0.f ? o.x : expm1f(o.x);
      o.y = o.y > 0.f ? o.y : expm1f(o.y);
      o.z = o.z > 0.f ? o.z : expm1f(o.z);
      o.w = o.w > 0.f ? o.w : expm1f(o.w);
      ((float4*)&h1[(size_t)n*C1])[t] = o;
    }
    return;
  }

  // fallback (deg > CAP1): 3-pass recompute, column-per-thread — correctness path, ~never taken
  {
    float m0 = -INFINITY, m1 = -INFINITY, la0 = 0.f, la1 = 0.f;
    for (int i = t; i < deg; i += 128){
      float4 r = erec[(size_t)beg + i];
      int s = __float_as_int(r.x);
      float2 a = *(const float2*)&as1[s*2];
      m0 = fmaxf(m0, lrelu(a.x + ad0  + r.y));
      m1 = fmaxf(m1, lrelu(a.y + adv1 + r.z));
      la0 += r.y; la1 += r.z;
    }
    for (int off = 1; off < 64; off <<= 1){
      m0 = fmaxf(m0, __shfl_xor(m0, off));
      m1 = fmaxf(m1, __shfl_xor(m1, off));
      la0 += __shfl_xor(la0, off); la1 += __shfl_xor(la1, off);
    }
    if (lane == 0){ mW[w][0]=m0; mW[w][1]=m1; laW[w][0]=la0; laW[w][1]=la1; }
    __syncthreads();
    M0 = fmaxf(mW[0][0], mW[1][0]);
    M1 = fmaxf(mW[0][1], mW[1][1]);
    sl0 = lrelu(as1[n*2+0] + ad0  + (laW[0][0]+laW[1][0])*inv);
    sl1 = lrelu(as1[n*2+1] + adv1 + (laW[0][1]+laW[1][1])*inv);
    M0 = fmaxf(M0, sl0); M1 = fmaxf(M1, sl1);
    float s0 = 0.f, s1 = 0.f;
    for (int i = t; i < deg; i += 128){
      float4 r = erec[(size_t)beg + i];
      int s = __float_as_int(r.x);
      float2 a = *(const float2*)&as1[s*2];
      s0 += expf(lrelu(a.x + ad0  + r.y) - M0);
      s1 += expf(lrelu(a.y + adv1 + r.z) - M1);
    }
    for (int off = 1; off < 64; off <<= 1){
      s0 += __shfl_xor(s0, off); s1 += __shfl_xor(s1, off);
    }
    if (lane == 0){ sW[w][0]=s0; sW[w][1]=s1; }
    __syncthreads();
    es0 = expf(sl0 - M0); es1 = expf(sl1 - M1);
    S0 = sW[0][0] + sW[1][0] + es0;
    S1 = sW[0][1] + sW[1][1] + es1;
    const float* eSel = (t < 64) ? e0A : e1A;
    float acc = 0.f;
    for (int base = 0; base < deg; base += CAP1){
      int c = min(CAP1, deg - base);
      __syncthreads();
      for (int i = t; i < c; i += 128){
        float4 r = erec[(size_t)beg + base + i];
        int s = __float_as_int(r.x);
        float2 a = *(const float2*)&as1[s*2];
        srcA[i] = s * C1;
        e0A[i] = expf(lrelu(a.x + ad0  + r.y) - M0);
        e1A[i] = expf(lrelu(a.y + adv1 + r.z) - M1);
      }
      __syncthreads();
      for (int k = 0; k < c; ++k)
        acc += eSel[k] * xh[(size_t)(srcA[k] + t)];
    }
    acc += ((t < 64) ? es0 : es1) * xh[(size_t)n*C1 + t];
    float v = acc / (((t < 64) ? S0 : S1) + 1e-16f) + b1[t];
    h1[(size_t)n*C1 + t] = v > 0.f ? v : expm1f(v);   // ELU
  }
}

// ---------------- K8: xh2 = h1 @ W2 ([N,128]@[128,40]) ----------------
#define G2_ROWS 6
__global__ void __launch_bounds__(256) k_gemm2(const float* __restrict__ h1,
                                               const float* __restrict__ W2,
                                               float* __restrict__ xh2){
  __shared__ float wt[F_IN*OUT_C];
  __shared__ float xt[G2_ROWS][F_IN];
  int t = threadIdx.x;
  for (int i = t; i < F_IN*OUT_C; i += 256) wt[i] = W2[i];
  int r0 = blockIdx.x * G2_ROWS;
  for (int i = t; i < G2_ROWS*F_IN; i += 256){
    int r = i >> 7, c = i & 127;
    int row = r0 + r;
    xt[r][c] = (row < N_NODES) ? h1[(size_t)row*F_IN + c] : 0.f;
  }
  __syncthreads();
  if (t < G2_ROWS*OUT_C){
    int lr = t / OUT_C, c = t % OUT_C;
    int row = r0 + lr;
    if (row < N_NODES){
      float acc = 0.f;
      for (int k = 0; k < F_IN; k += 4){
        float4 xv = *(const float4*)&xt[lr][k];
        acc += xv.x*wt[(k+0)*OUT_C + c] + xv.y*wt[(k+1)*OUT_C + c]
             + xv.z*wt[(k+2)*OUT_C + c] + xv.w*wt[(k+3)*OUT_C + c];
      }
      xh2[(size_t)row*OUT_C + c] = acc;
    }
  }
}

// ---------------- K9: per-node attention scalars layer 2 ----------------
__global__ void k_att2(const float* __restrict__ xh2, const float* __restrict__ a_src,
                       const float* __restrict__ a_dst,
                       float* __restrict__ as_o, float* __restrict__ ad_o){
  int node = blockIdx.x * (blockDim.x >> 6) + (threadIdx.x >> 6);
  int lane = threadIdx.x & 63;
  if (node >= N_NODES) return;
  float v = (lane < OUT_C) ? xh2[(size_t)node*OUT_C + lane] : 0.f;
  float s = (lane < OUT_C) ? v*a_src[lane] : 0.f;
  float d = (lane < OUT_C) ? v*a_dst[lane] : 0.f;
  for (int off = 1; off < 64; off <<= 1){
    s += __shfl_xor(s, off);
    d += __shfl_xor(d, off);
  }
  if (lane == 0){ as_o[node] = s; ad_o[node] = d; }
}

// ---------------- K10: layer-2 aggregation + log_softmax, 4-way ILP gather ----------------
__global__ void __launch_bounds__(64) k_agg2(const float* __restrict__ xh2,
    const int* __restrict__ rowptr, const float4* __restrict__ erec,
    const float* __restrict__ as2, const float* __restrict__ ad2,
    const float* __restrict__ b2, float* __restrict__ out){
  __shared__ int   srcA[CAP2];
  __shared__ float eA[CAP2];
  int n = blockIdx.x, t = threadIdx.x;
  int beg = rowptr[n], end = rowptr[n+1];
  int deg = end - beg;
  float adv = ad2[n];
  float inv = 1.f / fmaxf((float)deg, 1.f);
  float M, sl, es, S;
  float acc = 0.f;

  if (deg <= CAP2){
    float m = -INFINITY, la = 0.f;
    for (int i = t; i < deg; i += 64){
      float4 r = erec[(size_t)beg + i];
      int s = __float_as_int(r.x);
      float lg = lrelu(as2[s] + adv + r.w);
      srcA[i] = s * OUT_C;
      eA[i] = lg;
      m = fmaxf(m, lg);
      la += r.w;
    }
    for (int off = 1; off < 64; off <<= 1){
      m = fmaxf(m, __shfl_xor(m, off));
      la += __shfl_xor(la, off);
    }
    sl = lrelu(as2[n] + adv + la*inv);
    M = fmaxf(m, sl);
    float ss = 0.f;
    __syncthreads();
    for (int i = t; i < deg; i += 64){
      float e = expf(eA[i] - M);
      eA[i] = e;
      ss += e;
    }
    for (int off = 1; off < 64; off <<= 1) ss += __shfl_xor(ss, off);
    es = expf(sl - M);
    S = ss + es;
    __syncthreads();
    if (t < OUT_C){
      float a0 = 0.f, a1 = 0.f, a2 = 0.f, a3 = 0.f;
      int k = 0;
      for (; k + 4 <= deg; k += 4){
        a0 += eA[k+0] * xh2[(size_t)(srcA[k+0] + t)];
        a1 += eA[k+1] * xh2[(size_t)(srcA[k+1] + t)];
        a2 += eA[k+2] * xh2[(size_t)(srcA[k+2] + t)];
        a3 += eA[k+3] * xh2[(size_t)(srcA[k+3] + t)];
      }
      for (; k < deg; ++k) a0 += eA[k] * xh2[(size_t)(srcA[k] + t)];
      acc = (a0 + a1) + (a2 + a3);
    }
  } else {
    // fallback, ~never taken
    float m = -INFINITY, la = 0.f;
    for (int i = t; i < deg; i += 64){
      float4 r = erec[(size_t)beg + i];
      int s = __float_as_int(r.x);
      m = fmaxf(m, lrelu(as2[s] + adv + r.w));
      la += r.w;
    }
    for (int off = 1; off < 64; off <<= 1){
      m = fmaxf(m, __shfl_xor(m, off));
      la += __shfl_xor(la, off);
    }
    sl = lrelu(as2[n] + adv + la*inv);
    M = fmaxf(m, sl);
    float ss = 0.f;
    for (int i = t; i < deg; i += 64){
      float4 r = erec[(size_t)beg + i];
      int s = __float_as_int(r.x);
      ss += expf(lrelu(as2[s] + adv + r.w) - M);
    }
    for (int off = 1; off < 64; off <<= 1) ss += __shfl_xor(ss, off);
    es = expf(sl - M);
    S = ss + es;
    for (int base = 0; base < deg; base += CAP2){
      int c = min(CAP2, deg - base);
      __syncthreads();
      for (int i = t; i < c; i += 64){
        float4 r = erec[(size_t)beg + base + i];
        int s = __float_as_int(r.x);
        srcA[i] = s * OUT_C;
        eA[i] = expf(lrelu(as2[s] + adv + r.w) - M);
      }
      __syncthreads();
      if (t < OUT_C)
        for (int k = 0; k < c; ++k) acc += eA[k] * xh2[(size_t)(srcA[k] + t)];
    }
  }
  float o;
  if (t < OUT_C){
    acc += es * xh2[(size_t)n*OUT_C + t];
    o = acc / (S + 1e-16f) + b2[t];
  } else {
    o = -INFINITY;
  }
  // log_softmax over the 40 columns
  float mm = o;
  for (int off = 1; off < 64; off <<= 1) mm = fmaxf(mm, __shfl_xor(mm, off));
  float e = (t < OUT_C) ? expf(o - mm) : 0.f;
  for (int off = 1; off < 64; off <<= 1) e += __shfl_xor(e, off);
  if (t < OUT_C) out[(size_t)n*OUT_C + t] = o - mm - logf(e);
}

// ---------------- host launcher ----------------
extern "C" void kernel_launch(void* const* d_in, const int* in_sizes, int n_in,
                              void* d_out, int out_size, void* d_ws, size_t ws_size,
                              hipStream_t stream){
  const float* x        = (const float*)d_in[0];
  const int*   ei       = (const int*)  d_in[1];
  const float* eattr    = (const float*)d_in[2];
  const float* W1       = (const float*)d_in[3];
  const float* att_src1 = (const float*)d_in[4];
  const float* att_dst1 = (const float*)d_in[5];
  const float* We1      = (const float*)d_in[6];
  const float* att_e1   = (const float*)d_in[7];
  const float* b1       = (const float*)d_in[8];
  const float* W2       = (const float*)d_in[9];
  const float* att_src2 = (const float*)d_in[10];
  const float* att_dst2 = (const float*)d_in[11];
  const float* We2      = (const float*)d_in[12];
  const float* att_e2   = (const float*)d_in[13];
  const float* b2       = (const float*)d_in[14];
  const int* src = ei;
  const int* dst = ei + N_EDGES;

  float* wsf    = (float*)d_ws;
  int*   cnt     = (int*)(wsf + O_CNT);
  int*   fill    = (int*)(wsf + O_FILL);
  int*   rowptr  = (int*)(wsf + O_ROWPTR);
  int*   stmp    = (int*)(wsf + O_STMP);
  int*   bsum    = (int*)(wsf + O_BSUM);
  int*   boff    = (int*)(wsf + O_BOFF);
  float4* erec   = (float4*)(wsf + O_EREC);
  float* weatt   = wsf + O_WEATT;
  float* xh1     = wsf + O_XH1;
  float* as1     = wsf + O_AS1;
  float* ad1     = wsf + O_AD1;
  float* h1      = wsf + O_H1;
  float* xh2     = wsf + O_XH2;
  float* as2     = wsf + O_AS2;
  float* ad2     = wsf + O_AD2;
  float* out     = (float*)d_out;

  hipMemsetAsync(wsf + O_CNT, 0, O_ZERO_END*sizeof(float), stream);

  const int EB = (N_EDGES + 255) / 256;

  k_weatt  <<<1, 64, 0, stream>>>(We1, att_e1, We2, att_e2, weatt);
  k_count  <<<EB, 256, 0, stream>>>(dst, cnt);
  k_scan1  <<<SCAN_NB, SCAN_B, 0, stream>>>(cnt, stmp, bsum);
  k_scan2  <<<1, SCAN_B, 0, stream>>>(bsum, boff);
  k_scan3  <<<SCAN_NB, SCAN_B, 0, stream>>>(stmp, boff, rowptr);
  k_scatter<<<EB, 256, 0, stream>>>(src, dst, eattr, rowptr, fill, weatt, erec);

  k_gemm1  <<<(N_NODES + G1_ROWS - 1)/G1_ROWS, 128, 0, stream>>>(x, W1, xh1);
  k_att1   <<<(N_NODES + 3)/4, 256, 0, stream>>>(xh1, att_src1, att_dst1, as1, ad1);
  k_agg1   <<<N_NODES, 128, 0, stream>>>(xh1, rowptr, erec, as1, ad1, b1, h1);

  k_gemm2  <<<(N_NODES + G2_ROWS - 1)/G2_ROWS, 256, 0, stream>>>(h1, W2, xh2);
  k_att2   <<<(N_NODES + 3)/4, 256, 0, stream>>>(xh2, att_src2, att_dst2, as2, ad2);
  k_agg2   <<<N_NODES, 64, 0, stream>>>(xh2, rowptr, erec, as2, ad2, b2, out);
}

// Round 6
// 270.664 us; speedup vs baseline: 2.5437x; 1.2771x over previous
//
#include <hip/hip_runtime.h>
#include <math.h>

#define N_NODES 50000
#define N_EDGES 800000
#define F_IN    128
#define HID     64
#define HEADS   2
#define C1      128   // HEADS*HID
#define OUT_C   40
#define EDIM    5
#define NEG_SLOPE 0.2f
#define CAP1    768   // LDS edge cache, layer-1 agg (Poisson(16) => never exceeded; fallback kept)
#define CAP2    512   // LDS edge cache, layer-2 agg
#define SCAN_B  256
#define SCAN_NB ((N_NODES + SCAN_B - 1) / SCAN_B)   // 196

// ---------------- workspace layout (element offsets, 4B units) ----------------
constexpr size_t pad64(size_t n){ return (n + 63) / 64 * 64; }
constexpr size_t O_CNT      = 0;
constexpr size_t O_FILL     = O_CNT      + pad64(N_NODES);
constexpr size_t O_ZERO_END = O_FILL     + pad64(N_NODES);
constexpr size_t O_ROWPTR   = O_ZERO_END;
constexpr size_t O_STMP     = O_ROWPTR   + pad64(N_NODES+1);
constexpr size_t O_BSUM     = O_STMP     + pad64(N_NODES);
constexpr size_t O_BOFF     = O_BSUM     + pad64(SCAN_NB);
constexpr size_t O_EREC     = O_BOFF     + pad64(SCAN_NB);    // float4 per edge {src, l1h0, l1h1, l2}
constexpr size_t O_WEATT    = O_EREC     + pad64((size_t)N_EDGES*4);
constexpr size_t O_XH1      = O_WEATT    + 64;
constexpr size_t O_AS1      = O_XH1      + pad64((size_t)N_NODES*C1);
constexpr size_t O_AD1      = O_AS1      + pad64((size_t)N_NODES*2);
constexpr size_t O_H1       = O_AD1      + pad64((size_t)N_NODES*2);
constexpr size_t O_XH2      = O_H1       + pad64((size_t)N_NODES*C1);
constexpr size_t O_AS2      = O_XH2      + pad64((size_t)N_NODES*OUT_C);
constexpr size_t O_AD2      = O_AS2      + pad64(N_NODES);

__device__ __forceinline__ float lrelu(float v){ return v >= 0.f ? v : NEG_SLOPE*v; }

// ---------------- K0: tiny attention-projection matrices ----------------
__global__ void k_weatt(const float* __restrict__ We1, const float* __restrict__ ae1,
                        const float* __restrict__ We2, const float* __restrict__ ae2,
                        float* __restrict__ weatt){
  int t = threadIdx.x;
  if (t < 10){
    int k = t >> 1, h = t & 1;
    float s = 0.f;
    for (int c = 0; c < HID; c++) s += We1[k*C1 + h*HID + c] * ae1[h*HID + c];
    weatt[k*2 + h] = s;
  } else if (t < 15){
    int k = t - 10;
    float s = 0.f;
    for (int c = 0; c < OUT_C; c++) s += We2[k*OUT_C + c] * ae2[c];
    weatt[10 + k] = s;
  }
}

// ---------------- K1: in-degree (int atomics, L2-resident) ----------------
__global__ void k_count(const int* __restrict__ dst, int* __restrict__ cnt){
  int e = blockIdx.x*blockDim.x + threadIdx.x;
  if (e >= N_EDGES) return;
  atomicAdd(&cnt[dst[e]], 1);
}

// ---------------- K2: device-wide exclusive scan, 3 wide dispatches ----------------
__global__ void __launch_bounds__(SCAN_B) k_scan1(const int* __restrict__ cnt,
                                                  int* __restrict__ stmp,
                                                  int* __restrict__ bsum){
  int blk = blockIdx.x, t = threadIdx.x;
  int i = blk*SCAN_B + t;
  int v = (i < N_NODES) ? cnt[i] : 0;
  int lane = t & 63, w = t >> 6;
  int x = v;
  #pragma unroll
  for (int off = 1; off < 64; off <<= 1){
    int y = __shfl_up(x, off);
    if (lane >= off) x += y;
  }
  __shared__ int wsum[SCAN_B/64];
  if (lane == 63) wsum[w] = x;
  __syncthreads();
  int add = 0;
  for (int k = 0; k < w; k++) add += wsum[k];
  x += add;
  if (i < N_NODES) stmp[i] = x;
  if (t == SCAN_B-1) bsum[blk] = x;
}

__global__ void __launch_bounds__(SCAN_B) k_scan2(const int* __restrict__ bsum,
                                                  int* __restrict__ boff){
  int t = threadIdx.x;
  int v = (t < SCAN_NB) ? bsum[t] : 0;
  int lane = t & 63, w = t >> 6;
  int x = v;
  #pragma unroll
  for (int off = 1; off < 64; off <<= 1){
    int y = __shfl_up(x, off);
    if (lane >= off) x += y;
  }
  __shared__ int wsum[SCAN_B/64];
  if (lane == 63) wsum[w] = x;
  __syncthreads();
  int add = 0;
  for (int k = 0; k < w; k++) add += wsum[k];
  x += add;                      // inclusive
  if (t < SCAN_NB) boff[t] = x - v;  // exclusive
}

__global__ void __launch_bounds__(SCAN_B) k_scan3(const int* __restrict__ stmp,
                                                  const int* __restrict__ boff,
                                                  int* __restrict__ rowptr){
  int blk = blockIdx.x, t = threadIdx.x;
  int i = blk*SCAN_B + t;
  if (i < N_NODES) rowptr[i+1] = stmp[i] + boff[blk];
  if (i == 0) rowptr[0] = 0;
}

// ---------------- K3: scatter edges into CSR as interleaved float4 records ----------------
__global__ void k_scatter(const int* __restrict__ src, const int* __restrict__ dst,
                          const float* __restrict__ eattr, const int* __restrict__ rowptr,
                          int* __restrict__ fill, const float* __restrict__ weatt,
                          float4* __restrict__ erec){
  int e = blockIdx.x*blockDim.x + threadIdx.x;
  if (e >= N_EDGES) return;
  int d = dst[e];
  int pos = rowptr[d] + atomicAdd(&fill[d], 1);
  float a[EDIM];
  #pragma unroll
  for (int k = 0; k < EDIM; k++) a[k] = eattr[e*EDIM + k];
  float l0 = 0.f, l1 = 0.f, l2 = 0.f;
  #pragma unroll
  for (int k = 0; k < EDIM; k++){
    l0 += a[k]*weatt[k*2 + 0];
    l1 += a[k]*weatt[k*2 + 1];
    l2 += a[k]*weatt[10 + k];
  }
  erec[pos] = make_float4(__int_as_float(src[e]), l0, l1, l2);
}

// ---------------- K5: xh1 = x @ W1 (register-tiled 128x128, fused att1) ----------------
// block 256 = 16 tx (8 cols each) x 16 ty (8 rows each); tile 128 rows x 128 cols
#define T1_ROWS 128
#define T1_KK   32
__global__ void __launch_bounds__(256) k_gemm1(const float* __restrict__ x,
                                               const float* __restrict__ W,
                                               const float* __restrict__ a_src,
                                               const float* __restrict__ a_dst,
                                               float* __restrict__ xh,
                                               float* __restrict__ as_o,
                                               float* __restrict__ ad_o){
  __shared__ float xs[T1_ROWS][T1_KK+1];
  __shared__ float ws[T1_KK][C1];
  int tid = threadIdx.x;
  int tx = tid & 15, ty = tid >> 4;
  int r0 = blockIdx.x * T1_ROWS;
  float acc[8][8];
  #pragma unroll
  for (int i = 0; i < 8; i++)
    #pragma unroll
    for (int j = 0; j < 8; j++) acc[i][j] = 0.f;

  for (int kb = 0; kb < F_IN; kb += T1_KK){
    __syncthreads();
    // stage x tile: 128 rows x 32 k = 1024 float4
    for (int i = tid; i < T1_ROWS*(T1_KK/4); i += 256){
      int r = i >> 3, c4 = (i & 7) * 4;
      int row = r0 + r;
      float4 v = (row < N_NODES) ? *(const float4*)&x[(size_t)row*F_IN + kb + c4]
                                 : make_float4(0.f,0.f,0.f,0.f);
      xs[r][c4+0]=v.x; xs[r][c4+1]=v.y; xs[r][c4+2]=v.z; xs[r][c4+3]=v.w;
    }
    // stage W tile: 32 k x 128 c
    for (int i = tid; i < T1_KK*(C1/4); i += 256){
      int k = i >> 5, c4 = (i & 31) * 4;
      *(float4*)&ws[k][c4] = *(const float4*)&W[(size_t)(kb + k)*C1 + c4];
    }
    __syncthreads();
    #pragma unroll 4
    for (int k = 0; k < T1_KK; k++){
      float a[8], b[8];
      #pragma unroll
      for (int i = 0; i < 8; i++) a[i] = xs[ty*8 + i][k];
      float4 b0 = *(const float4*)&ws[k][tx*8];
      float4 b1 = *(const float4*)&ws[k][tx*8+4];
      b[0]=b0.x; b[1]=b0.y; b[2]=b0.z; b[3]=b0.w;
      b[4]=b1.x; b[5]=b1.y; b[6]=b1.z; b[7]=b1.w;
      #pragma unroll
      for (int i = 0; i < 8; i++)
        #pragma unroll
        for (int j = 0; j < 8; j++)
          acc[i][j] += a[i]*b[j];
    }
  }
  // epilogue: store xh + fused att projections (head0 = tx 0..7, head1 = tx 8..15)
  float asv[8], adv[8];
  #pragma unroll
  for (int j = 0; j < 8; j++){
    asv[j] = a_src[tx*8 + j];
    adv[j] = a_dst[tx*8 + j];
  }
  int h = tx >> 3;
  #pragma unroll
  for (int i = 0; i < 8; i++){
    int row = r0 + ty*8 + i;
    bool ok = row < N_NODES;
    if (ok){
      float4 o0 = make_float4(acc[i][0], acc[i][1], acc[i][2], acc[i][3]);
      float4 o1 = make_float4(acc[i][4], acc[i][5], acc[i][6], acc[i][7]);
      *(float4*)&xh[(size_t)row*C1 + tx*8]     = o0;
      *(float4*)&xh[(size_t)row*C1 + tx*8 + 4] = o1;
    }
    float s = 0.f, d = 0.f;
    #pragma unroll
    for (int j = 0; j < 8; j++){ s += acc[i][j]*asv[j]; d += acc[i][j]*adv[j]; }
    s += __shfl_xor(s, 1); s += __shfl_xor(s, 2); s += __shfl_xor(s, 4);
    d += __shfl_xor(d, 1); d += __shfl_xor(d, 2); d += __shfl_xor(d, 4);
    if (ok && (tx & 7) == 0){
      as_o[row*2 + h] = s;
      ad_o[row*2 + h] = d;
    }
  }
}

// ---------------- K7: layer-1 aggregation; phase-B = 4 edges in flight, float4 lanes ----------------
__global__ void __launch_bounds__(128) k_agg1(const float* __restrict__ xh,
    const int* __restrict__ rowptr, const float4* __restrict__ erec,
    const float* __restrict__ as1, const float* __restrict__ ad1,
    const float* __restrict__ b1, float* __restrict__ h1){
  __shared__ int   srcA[CAP1];
  __shared__ float e0A[CAP1], e1A[CAP1];
  __shared__ float mW[2][2], laW[2][2], sW[2][2];
  __shared__ float4 redL[32];
  int n = blockIdx.x, t = threadIdx.x;
  int w = t >> 6, lane = t & 63;
  int beg = rowptr[n], end = rowptr[n+1];
  int deg = end - beg;
  float ad0 = ad1[n*2+0], adv1 = ad1[n*2+1];
  float inv = 1.f / fmaxf((float)deg, 1.f);
  float M0, M1, sl0, sl1, es0, es1, S0, S1;

  if (deg <= CAP1){
    // pass A: logits -> LDS, plain max + ale-sum reduce
    float m0 = -INFINITY, m1 = -INFINITY, la0 = 0.f, la1 = 0.f;
    for (int i = t; i < deg; i += 128){
      float4 r = erec[(size_t)beg + i];
      int s = __float_as_int(r.x);
      float2 a = *(const float2*)&as1[s*2];
      float lg0 = lrelu(a.x + ad0  + r.y);
      float lg1 = lrelu(a.y + adv1 + r.z);
      srcA[i] = s * C1;
      e0A[i] = lg0; e1A[i] = lg1;
      m0 = fmaxf(m0, lg0); m1 = fmaxf(m1, lg1);
      la0 += r.y; la1 += r.z;
    }
    for (int off = 1; off < 64; off <<= 1){
      m0 = fmaxf(m0, __shfl_xor(m0, off));
      m1 = fmaxf(m1, __shfl_xor(m1, off));
      la0 += __shfl_xor(la0, off); la1 += __shfl_xor(la1, off);
    }
    if (lane == 0){ mW[w][0]=m0; mW[w][1]=m1; laW[w][0]=la0; laW[w][1]=la1; }
    __syncthreads();
    M0 = fmaxf(mW[0][0], mW[1][0]);
    M1 = fmaxf(mW[0][1], mW[1][1]);
    sl0 = lrelu(as1[n*2+0] + ad0  + (laW[0][0]+laW[1][0])*inv);
    sl1 = lrelu(as1[n*2+1] + adv1 + (laW[0][1]+laW[1][1])*inv);
    M0 = fmaxf(M0, sl0); M1 = fmaxf(M1, sl1);
    // pass A2: one exp per edge, stored in place (own slots only)
    float s0 = 0.f, s1 = 0.f;
    for (int i = t; i < deg; i += 128){
      float e0 = expf(e0A[i] - M0);
      float e1 = expf(e1A[i] - M1);
      e0A[i] = e0; e1A[i] = e1;
      s0 += e0; s1 += e1;
    }
    for (int off = 1; off < 64; off <<= 1){
      s0 += __shfl_xor(s0, off); s1 += __shfl_xor(s1, off);
    }
    if (lane == 0){ sW[w][0]=s0; sW[w][1]=s1; }
    __syncthreads();
    es0 = expf(sl0 - M0); es1 = expf(sl1 - M1);
    S0 = sW[0][0] + sW[1][0] + es0;
    S1 = sW[0][1] + sW[1][1] + es1;
    // phase B: 4 edge-groups x 32 lanes; each lane = float4 of one source row
    int q = t >> 5, lane32 = t & 31;
    bool head0 = (lane32 < 16);
    float4 acc = make_float4(0.f, 0.f, 0.f, 0.f);
    for (int k0 = 0; k0 < deg; k0 += 4){
      int k = k0 + q;
      if (k < deg){
        float e = head0 ? e0A[k] : e1A[k];
        float4 r = ((const float4*)&xh[srcA[k]])[lane32];
        acc.x += e*r.x; acc.y += e*r.y; acc.z += e*r.z; acc.w += e*r.w;
      }
    }
    // combine group pairs within each wave (q0+q1 in wave0, q2+q3 in wave1)
    acc.x += __shfl_xor(acc.x, 32);
    acc.y += __shfl_xor(acc.y, 32);
    acc.z += __shfl_xor(acc.z, 32);
    acc.w += __shfl_xor(acc.w, 32);
    if (t >= 64 && t < 96) redL[t - 64] = acc;
    __syncthreads();
    if (t < 32){
      float4 r2 = redL[t];
      acc.x += r2.x; acc.y += r2.y; acc.z += r2.z; acc.w += r2.w;
      // self-loop + bias + ELU + store (cols t*4..t*4+3; head0 iff t<16)
      float es = head0 ? es0 : es1;
      float den = (head0 ? S0 : S1) + 1e-16f;
      float4 xs = ((const float4*)&xh[(size_t)n*C1])[t];
      float4 bv = ((const float4*)b1)[t];
      float4 o;
      o.x = (acc.x + es*xs.x)/den + bv.x;
      o.y = (acc.y + es*xs.y)/den + bv.y;
      o.z = (acc.z + es*xs.z)/den + bv.z;
      o.w = (acc.w + es*xs.w)/den + bv.w;
      o.x = o.x > 0.f ? o.x : expm1f(o.x);
      o.y = o.y > 0.f ? o.y : expm1f(o.y);
      o.z = o.z > 0.f ? o.z : expm1f(o.z);
      o.w = o.w > 0.f ? o.w : expm1f(o.w);
      ((float4*)&h1[(size_t)n*C1])[t] = o;
    }
    return;
  }

  // fallback (deg > CAP1): 3-pass recompute, column-per-thread — correctness path, ~never taken
  {
    float m0 = -INFINITY, m1 = -INFINITY, la0 = 0.f, la1 = 0.f;
    for (int i = t; i < deg; i += 128){
      float4 r = erec[(size_t)beg + i];
      int s = __float_as_int(r.x);
      float2 a = *(const float2*)&as1[s*2];
      m0 = fmaxf(m0, lrelu(a.x + ad0  + r.y));
      m1 = fmaxf(m1, lrelu(a.y + adv1 + r.z));
      la0 += r.y; la1 += r.z;
    }
    for (int off = 1; off < 64; off <<= 1){
      m0 = fmaxf(m0, __shfl_xor(m0, off));
      m1 = fmaxf(m1, __shfl_xor(m1, off));
      la0 += __shfl_xor(la0, off); la1 += __shfl_xor(la1, off);
    }
    if (lane == 0){ mW[w][0]=m0; mW[w][1]=m1; laW[w][0]=la0; laW[w][1]=la1; }
    __syncthreads();
    M0 = fmaxf(mW[0][0], mW[1][0]);
    M1 = fmaxf(mW[0][1], mW[1][1]);
    sl0 = lrelu(as1[n*2+0] + ad0  + (laW[0][0]+laW[1][0])*inv);
    sl1 = lrelu(as1[n*2+1] + adv1 + (laW[0][1]+laW[1][1])*inv);
    M0 = fmaxf(M0, sl0); M1 = fmaxf(M1, sl1);
    float s0 = 0.f, s1 = 0.f;
    for (int i = t; i < deg; i += 128){
      float4 r = erec[(size_t)beg + i];
      int s = __float_as_int(r.x);
      float2 a = *(const float2*)&as1[s*2];
      s0 += expf(lrelu(a.x + ad0  + r.y) - M0);
      s1 += expf(lrelu(a.y + adv1 + r.z) - M1);
    }
    for (int off = 1; off < 64; off <<= 1){
      s0 += __shfl_xor(s0, off); s1 += __shfl_xor(s1, off);
    }
    if (lane == 0){ sW[w][0]=s0; sW[w][1]=s1; }
    __syncthreads();
    es0 = expf(sl0 - M0); es1 = expf(sl1 - M1);
    S0 = sW[0][0] + sW[1][0] + es0;
    S1 = sW[0][1] + sW[1][1] + es1;
    const float* eSel = (t < 64) ? e0A : e1A;
    float acc = 0.f;
    for (int base = 0; base < deg; base += CAP1){
      int c = min(CAP1, deg - base);
      __syncthreads();
      for (int i = t; i < c; i += 128){
        float4 r = erec[(size_t)beg + base + i];
        int s = __float_as_int(r.x);
        float2 a = *(const float2*)&as1[s*2];
        srcA[i] = s * C1;
        e0A[i] = expf(lrelu(a.x + ad0  + r.y) - M0);
        e1A[i] = expf(lrelu(a.y + adv1 + r.z) - M1);
      }
      __syncthreads();
      for (int k = 0; k < c; ++k)
        acc += eSel[k] * xh[(size_t)(srcA[k] + t)];
    }
    acc += ((t < 64) ? es0 : es1) * xh[(size_t)n*C1 + t];
    float v = acc / (((t < 64) ? S0 : S1) + 1e-16f) + b1[t];
    h1[(size_t)n*C1 + t] = v > 0.f ? v : expm1f(v);   // ELU
  }
}

// ---------------- K8: xh2 = h1 @ W2 (register-tiled, fused att2) ----------------
// block 256 = 8 tx (5 cols each) x 32 ty (4 rows each); tile 128 rows x 40 cols
#define T2_ROWS 128
#define T2_KK   32
__global__ void __launch_bounds__(256) k_gemm2(const float* __restrict__ h1,
    const float* __restrict__ W2, const float* __restrict__ a_src2,
    const float* __restrict__ a_dst2,
    float* __restrict__ xh2, float* __restrict__ as_o, float* __restrict__ ad_o){
  __shared__ float hs[T2_ROWS][T2_KK+1];
  __shared__ float ws[F_IN*OUT_C];     // full W2, 20.5 KB
  int tid = threadIdx.x;
  int tx = tid & 7, ty = tid >> 3;     // tx: 8 col-groups of 5, ty: 32 row-groups of 4
  int r0 = blockIdx.x * T2_ROWS;
  // stage W2 fully (1280 float4)
  for (int i = tid; i < F_IN*OUT_C/4; i += 256)
    ((float4*)ws)[i] = ((const float4*)W2)[i];
  float acc[4][5];
  #pragma unroll
  for (int i = 0; i < 4; i++)
    #pragma unroll
    for (int j = 0; j < 5; j++) acc[i][j] = 0.f;

  for (int kb = 0; kb < F_IN; kb += T2_KK){
    __syncthreads();                    // also covers ws staging before first use
    for (int i = tid; i < T2_ROWS*(T2_KK/4); i += 256){
      int r = i >> 3, c4 = (i & 7) * 4;
      int row = r0 + r;
      float4 v = (row < N_NODES) ? *(const float4*)&h1[(size_t)row*F_IN + kb + c4]
                                 : make_float4(0.f,0.f,0.f,0.f);
      hs[r][c4+0]=v.x; hs[r][c4+1]=v.y; hs[r][c4+2]=v.z; hs[r][c4+3]=v.w;
    }
    __syncthreads();
    #pragma unroll 4
    for (int k = 0; k < T2_KK; k++){
      float a[4], b[5];
      #pragma unroll
      for (int i = 0; i < 4; i++) a[i] = hs[ty*4 + i][k];
      #pragma unroll
      for (int j = 0; j < 5; j++) b[j] = ws[(kb + k)*OUT_C + tx*5 + j];
      #pragma unroll
      for (int i = 0; i < 4; i++)
        #pragma unroll
        for (int j = 0; j < 5; j++)
          acc[i][j] += a[i]*b[j];
    }
  }
  // epilogue: store xh2 + fused att2 (single head over all 40 cols)
  float asv[5], adv[5];
  #pragma unroll
  for (int j = 0; j < 5; j++){
    asv[j] = a_src2[tx*5 + j];
    adv[j] = a_dst2[tx*5 + j];
  }
  #pragma unroll
  for (int i = 0; i < 4; i++){
    int row = r0 + ty*4 + i;
    bool ok = row < N_NODES;
    if (ok){
      #pragma unroll
      for (int j = 0; j < 5; j++)
        xh2[(size_t)row*OUT_C + tx*5 + j] = acc[i][j];
    }
    float s = 0.f, d = 0.f;
    #pragma unroll
    for (int j = 0; j < 5; j++){ s += acc[i][j]*asv[j]; d += acc[i][j]*adv[j]; }
    s += __shfl_xor(s, 1); s += __shfl_xor(s, 2); s += __shfl_xor(s, 4);
    d += __shfl_xor(d, 1); d += __shfl_xor(d, 2); d += __shfl_xor(d, 4);
    if (ok && tx == 0){
      as_o[row] = s;
      ad_o[row] = d;
    }
  }
}

// ---------------- K10: layer-2 aggregation + log_softmax, 4-way ILP gather ----------------
__global__ void __launch_bounds__(64) k_agg2(const float* __restrict__ xh2,
    const int* __restrict__ rowptr, const float4* __restrict__ erec,
    const float* __restrict__ as2, const float* __restrict__ ad2,
    const float* __restrict__ b2, float* __restrict__ out){
  __shared__ int   srcA[CAP2];
  __shared__ float eA[CAP2];
  int n = blockIdx.x, t = threadIdx.x;
  int beg = rowptr[n], end = rowptr[n+1];
  int deg = end - beg;
  float adv = ad2[n];
  float inv = 1.f / fmaxf((float)deg, 1.f);
  float M, sl, es, S;
  float acc = 0.f;

  if (deg <= CAP2){
    float m = -INFINITY, la = 0.f;
    for (int i = t; i < deg; i += 64){
      float4 r = erec[(size_t)beg + i];
      int s = __float_as_int(r.x);
      float lg = lrelu(as2[s] + adv + r.w);
      srcA[i] = s * OUT_C;
      eA[i] = lg;
      m = fmaxf(m, lg);
      la += r.w;
    }
    for (int off = 1; off < 64; off <<= 1){
      m = fmaxf(m, __shfl_xor(m, off));
      la += __shfl_xor(la, off);
    }
    sl = lrelu(as2[n] + adv + la*inv);
    M = fmaxf(m, sl);
    float ss = 0.f;
    __syncthreads();
    for (int i = t; i < deg; i += 64){
      float e = expf(eA[i] - M);
      eA[i] = e;
      ss += e;
    }
    for (int off = 1; off < 64; off <<= 1) ss += __shfl_xor(ss, off);
    es = expf(sl - M);
    S = ss + es;
    __syncthreads();
    if (t < OUT_C){
      float a0 = 0.f, a1 = 0.f, a2 = 0.f, a3 = 0.f;
      int k = 0;
      for (; k + 4 <= deg; k += 4){
        a0 += eA[k+0] * xh2[(size_t)(srcA[k+0] + t)];
        a1 += eA[k+1] * xh2[(size_t)(srcA[k+1] + t)];
        a2 += eA[k+2] * xh2[(size_t)(srcA[k+2] + t)];
        a3 += eA[k+3] * xh2[(size_t)(srcA[k+3] + t)];
      }
      for (; k < deg; ++k) a0 += eA[k] * xh2[(size_t)(srcA[k] + t)];
      acc = (a0 + a1) + (a2 + a3);
    }
  } else {
    // fallback, ~never taken
    float m = -INFINITY, la = 0.f;
    for (int i = t; i < deg; i += 64){
      float4 r = erec[(size_t)beg + i];
      int s = __float_as_int(r.x);
      m = fmaxf(m, lrelu(as2[s] + adv + r.w));
      la += r.w;
    }
    for (int off = 1; off < 64; off <<= 1){
      m = fmaxf(m, __shfl_xor(m, off));
      la += __shfl_xor(la, off);
    }
    sl = lrelu(as2[n] + adv + la*inv);
    M = fmaxf(m, sl);
    float ss = 0.f;
    for (int i = t; i < deg; i += 64){
      float4 r = erec[(size_t)beg + i];
      int s = __float_as_int(r.x);
      ss += expf(lrelu(as2[s] + adv + r.w) - M);
    }
    for (int off = 1; off < 64; off <<= 1) ss += __shfl_xor(ss, off);
    es = expf(sl - M);
    S = ss + es;
    for (int base = 0; base < deg; base += CAP2){
      int c = min(CAP2, deg - base);
      __syncthreads();
      for (int i = t; i < c; i += 64){
        float4 r = erec[(size_t)beg + base + i];
        int s = __float_as_int(r.x);
        srcA[i] = s * OUT_C;
        eA[i] = expf(lrelu(as2[s] + adv + r.w) - M);
      }
      __syncthreads();
      if (t < OUT_C)
        for (int k = 0; k < c; ++k) acc += eA[k] * xh2[(size_t)(srcA[k] + t)];
    }
  }
  float o;
  if (t < OUT_C){
    acc += es * xh2[(size_t)n*OUT_C + t];
    o = acc / (S + 1e-16f) + b2[t];
  } else {
    o = -INFINITY;
  }
  // log_softmax over the 40 columns
  float mm = o;
  for (int off = 1; off < 64; off <<= 1) mm = fmaxf(mm, __shfl_xor(mm, off));
  float e = (t < OUT_C) ? expf(o - mm) : 0.f;
  for (int off = 1; off < 64; off <<= 1) e += __shfl_xor(e, off);
  if (t < OUT_C) out[(size_t)n*OUT_C + t] = o - mm - logf(e);
}

// ---------------- host launcher ----------------
extern "C" void kernel_launch(void* const* d_in, const int* in_sizes, int n_in,
                              void* d_out, int out_size, void* d_ws, size_t ws_size,
                              hipStream_t stream){
  const float* x        = (const float*)d_in[0];
  const int*   ei       = (const int*)  d_in[1];
  const float* eattr    = (const float*)d_in[2];
  const float* W1       = (const float*)d_in[3];
  const float* att_src1 = (const float*)d_in[4];
  const float* att_dst1 = (const float*)d_in[5];
  const float* We1      = (const float*)d_in[6];
  const float* att_e1   = (const float*)d_in[7];
  const float* b1       = (const float*)d_in[8];
  const float* W2       = (const float*)d_in[9];
  const float* att_src2 = (const float*)d_in[10];
  const float* att_dst2 = (const float*)d_in[11];
  const float* We2      = (const float*)d_in[12];
  const float* att_e2   = (const float*)d_in[13];
  const float* b2       = (const float*)d_in[14];
  const int* src = ei;
  const int* dst = ei + N_EDGES;

  float* wsf    = (float*)d_ws;
  int*   cnt     = (int*)(wsf + O_CNT);
  int*   fill    = (int*)(wsf + O_FILL);
  int*   rowptr  = (int*)(wsf + O_ROWPTR);
  int*   stmp    = (int*)(wsf + O_STMP);
  int*   bsum    = (int*)(wsf + O_BSUM);
  int*   boff    = (int*)(wsf + O_BOFF);
  float4* erec   = (float4*)(wsf + O_EREC);
  float* weatt   = wsf + O_WEATT;
  float* xh1     = wsf + O_XH1;
  float* as1     = wsf + O_AS1;
  float* ad1     = wsf + O_AD1;
  float* h1      = wsf + O_H1;
  float* xh2     = wsf + O_XH2;
  float* as2     = wsf + O_AS2;
  float* ad2     = wsf + O_AD2;
  float* out     = (float*)d_out;

  hipMemsetAsync(wsf + O_CNT, 0, O_ZERO_END*sizeof(float), stream);

  const int EB = (N_EDGES + 255) / 256;

  k_weatt  <<<1, 64, 0, stream>>>(We1, att_e1, We2, att_e2, weatt);
  k_count  <<<EB, 256, 0, stream>>>(dst, cnt);
  k_scan1  <<<SCAN_NB, SCAN_B, 0, stream>>>(cnt, stmp, bsum);
  k_scan2  <<<1, SCAN_B, 0, stream>>>(bsum, boff);
  k_scan3  <<<SCAN_NB, SCAN_B, 0, stream>>>(stmp, boff, rowptr);
  k_scatter<<<EB, 256, 0, stream>>>(src, dst, eattr, rowptr, fill, weatt, erec);

  k_gemm1  <<<(N_NODES + T1_ROWS - 1)/T1_ROWS, 256, 0, stream>>>(x, W1, att_src1, att_dst1,
                                                                 xh1, as1, ad1);
  k_agg1   <<<N_NODES, 128, 0, stream>>>(xh1, rowptr, erec, as1, ad1, b1, h1);

  k_gemm2  <<<(N_NODES + T2_ROWS - 1)/T2_ROWS, 256, 0, stream>>>(h1, W2, att_src2, att_dst2,
                                                                 xh2, as2, ad2);
  k_agg2   <<<N_NODES, 64, 0, stream>>>(xh2, rowptr, erec, as2, ad2, b2, out);
}